// Round 1
// baseline (25769.595 us; speedup 1.0000x reference)
//
#include <hip/hip_runtime.h>
#include <hip/hip_bf16.h>
#include <stdint.h>

// Problem constants
#define Bsz 512
#define Tsz 512
#define Fsz 16
#define Hsz 256
#define HORZ 24

// Decomposition: 3 layers x NG gate-slices x NBT batch-tiles
#define NG 8          // hidden-slice blocks per layer per batch tile
#define NBT 8         // batch tiles
#define BTILE 64      // batches per tile
#define USL 32        // hidden units per slice
#define GRW 128       // gate rows (=GEMM cols) per block
#define WROW_B 1024   // bytes per W LDS row (512 bf16)
#define WBYTES (GRW*WROW_B)     // 128 KiB
#define AROW_B 128    // bytes per A LDS row (64 bf16)
#define ABYTES (BTILE*AROW_B)   // 8 KiB per buffer
#define HBUF_ELEMS ((size_t)3*2*Bsz*Hsz)   // [layer][parity][b][H]
#define NFLAGS (3*NG*NBT)

typedef float  f32x4  __attribute__((ext_vector_type(4)));
typedef __bf16 bf16x8 __attribute__((ext_vector_type(8)));

__device__ __forceinline__ float sigm(float v){ return 1.f/(1.f+__expf(-v)); }
__device__ __forceinline__ float tanh_fast(float v){ return 1.f - 2.f/(1.f+__expf(2.f*v)); }

__global__ __launch_bounds__(512, 2) void lstm_persist(
    const float* __restrict__ xin,
    const float* __restrict__ Wih0,
    const float* __restrict__ Wih12,
    const float* __restrict__ Whh,
    const float* __restrict__ bih,
    const float* __restrict__ bhh,
    __bf16* __restrict__ hb,
    unsigned int* __restrict__ flags)
{
  __shared__ __align__(16) char smem[WBYTES + 2*ABYTES];   // 144 KiB

  const int bid = blockIdx.x;
  const int l   = bid >> 6;          // 0..2
  const int g   = (bid >> 3) & 7;    // gate-slice
  const int nb  = bid & 7;           // batch tile (stride-8 peers -> same XCD heuristic)
  const int tid = threadIdx.x;
  const int lane = tid & 63;
  const int wv   = tid >> 6;         // 0..7
  const int b0   = nb * BTILE;
  const int KC   = (l==0) ? 9 : 16;  // K chunks of 32 (l0: [x16|pad16|h256]=288)
  const int S    = (KC+1) >> 1;      // 64-wide K sections

  // ---- one-time: W slice -> LDS, bf16, [col][k] with XOR swizzle ----
  {
    const int c   = tid >> 2;        // 0..127 (col = interleaved unit*4+gate)
    const int q   = c & 3;           // gate: 0=i 1=f 2=g 3=o
    const int u   = c >> 2;          // local unit 0..31
    const int R   = q*Hsz + g*USL + u;   // row in the (1024 x K) weight
    const int sub = tid & 3;
    const int kmax = KC*32;
    for (int k0 = sub*8; k0 < kmax; k0 += 32) {
      __bf16 tmp[8] __attribute__((aligned(16)));
      #pragma unroll
      for (int j=0;j<8;++j) {
        int k = k0 + j;
        float w;
        if (l == 0) {
          if (k < Fsz)      w = Wih0[R*Fsz + k];
          else if (k < 32)  w = 0.f;
          else              w = Whh[(size_t)R*Hsz + (k-32)];
        } else {
          if (k < Hsz)      w = Wih12[((size_t)(l-1)*4*Hsz + R)*Hsz + k];
          else              w = Whh[((size_t)l*4*Hsz + R)*Hsz + (k-Hsz)];
        }
        tmp[j] = (__bf16)w;
      }
      int off = (k0*2) ^ ((c&7)<<4);
      *(bf16x8*)(smem + c*WROW_B + off) = *(bf16x8*)tmp;
    }
  }

  const int r15 = lane & 15;
  const int kg  = lane >> 4;
  const int cl  = wv*16 + r15;                       // this lane's GEMM col 0..127
  const int Rl  = (cl&3)*Hsz + g*USL + (cl>>2);
  const float bias = bih[l*4*Hsz + Rl] + bhh[l*4*Hsz + Rl];

  float cst[16];
  #pragma unroll
  for (int i=0;i<16;++i) cst[i]=0.f;

  unsigned int* myflag = flags + ((l*NG + g)*NBT + nb);
  __syncthreads();

  for (int t = 0; t < Tsz; ++t) {
    // ---- point-to-point waits (threads 0..23 poll, one flag each) ----
    {
      unsigned int* fp = nullptr; int target = 0;
      int grp = tid >> 3, gg = tid & 7;
      if      (grp == 0 && l > 0)              { fp = flags + (((l-1)*NG+gg)*NBT + nb); target = t+1; }
      else if (grp == 1 && t > 0)              { fp = flags + ((l*NG+gg)*NBT + nb);     target = t;   }
      else if (grp == 2 && l < 2 && t >= 2)    { fp = flags + (((l+1)*NG+gg)*NBT + nb); target = t-1; }
      if (fp) {
        int guard = 0;
        while ((int)__hip_atomic_load(fp, __ATOMIC_RELAXED, __HIP_MEMORY_SCOPE_AGENT) < target) {
          __builtin_amdgcn_s_sleep(1);
          if (++guard > (1<<22)) break;   // bailout: wrong result instead of hang
        }
        (void)__hip_atomic_load(fp, __ATOMIC_ACQUIRE, __HIP_MEMORY_SCOPE_AGENT);
      }
      __syncthreads();
    }

    const __bf16* hin  = (l>0) ? hb + ((size_t)((l-1)*2 + (t&1)))*Bsz*Hsz : (const __bf16*)nullptr;
    const __bf16* hrec = hb + ((size_t)(l*2 + ((t+1)&1)))*Bsz*Hsz;   // h_{l,t-1} (zeros at t=0)
    __bf16*       hout = hb + ((size_t)(l*2 + (t&1)))*Bsz*Hsz;

    // stage one 64-wide K section of A (64 rows) into LDS, swizzled
    auto stageA = [&](int s){
      char* ab = smem + WBYTES + (s&1)*ABYTES;
      int row = tid >> 3;
      int kp  = tid & 7;
      int k   = s*64 + kp*8;
      int gb  = b0 + row;
      bf16x8 v;
      if (l > 0) {
        const __bf16* src = (k < Hsz) ? (hin + (size_t)gb*Hsz + k)
                                      : (hrec + (size_t)gb*Hsz + (k - Hsz));
        v = *(const bf16x8*)src;
      } else {
        if (k < Fsz) {
          const float* xp = xin + ((size_t)gb*Tsz + t)*Fsz + k;
          #pragma unroll
          for (int j=0;j<8;++j) v[j] = (__bf16)xp[j];
        } else if (k < 32) {
          #pragma unroll
          for (int j=0;j<8;++j) v[j] = (__bf16)0.f;
        } else if (k < 288) {
          v = *(const bf16x8*)(hrec + (size_t)gb*Hsz + (k - 32));
        } else {
          #pragma unroll
          for (int j=0;j<8;++j) v[j] = (__bf16)0.f;
        }
      }
      int off = (kp*16) ^ ((row&7)<<4);
      *(bf16x8*)(ab + row*AROW_B + off) = v;
    };

    stageA(0);
    f32x4 acc[4];
    #pragma unroll
    for (int m=0;m<4;++m) acc[m] = (f32x4){0.f,0.f,0.f,0.f};
    __syncthreads();

    for (int s = 0; s < S; ++s) {
      if (s+1 < S) stageA(s+1);                      // prefetch next section
      const char* ab = smem + WBYTES + (s&1)*ABYTES;
      const int kcs = ((s*2+2) <= KC) ? 2 : 1;
      for (int kcl = 0; kcl < kcs; ++kcl) {
        int kk = (s*2 + kcl)*32 + kg*8;
        bf16x8 bfrag = *(const bf16x8*)(smem + cl*WROW_B + ((kk*2) ^ ((cl&7)<<4)));
        #pragma unroll
        for (int mt=0; mt<4; ++mt) {
          int arow = mt*16 + r15;
          int aoff = ((kcl*32 + kg*8)*2) ^ ((arow&7)<<4);
          bf16x8 afrag = *(const bf16x8*)(ab + arow*AROW_B + aoff);
          acc[mt] = __builtin_amdgcn_mfma_f32_16x16x32_bf16(afrag, bfrag, acc[mt], 0, 0, 0);
        }
      }
      __syncthreads();
    }

    // ---- epilogue: gather i,f,g,o across 4 neighbor lanes, f32 LSTM update ----
    #pragma unroll
    for (int mt=0; mt<4; ++mt) {
      #pragma unroll
      for (int rr=0; rr<4; ++rr) {
        float v  = acc[mt][rr] + bias;
        float vf = __shfl_xor(v, 1, 64);
        float vg = __shfl_xor(v, 2, 64);
        float vo = __shfl_xor(v, 3, 64);
        if ((lane & 3) == 0) {
          int idx = mt*4 + rr;
          float cn = sigm(vf)*cst[idx] + sigm(v)*tanh_fast(vg);
          cst[idx] = cn;
          float hv = sigm(vo)*tanh_fast(cn);
          int gb = b0 + mt*16 + kg*4 + rr;
          int ug = g*USL + (cl>>2);
          hout[(size_t)gb*Hsz + ug] = (__bf16)hv;
        }
      }
    }

    __threadfence();
    __syncthreads();
    if (tid == 0)
      __hip_atomic_store(myflag, (unsigned int)(t+1), __ATOMIC_RELEASE, __HIP_MEMORY_SCOPE_AGENT);
  }
}

__global__ void fc_kernel(const __bf16* __restrict__ hb,
                          const float* __restrict__ fcW,
                          const float* __restrict__ fcb,
                          float* __restrict__ out)
{
  __shared__ float hs[Hsz];
  int b = blockIdx.x;
  const __bf16* hp = hb + ((size_t)(2*2 + 1))*Bsz*Hsz + (size_t)b*Hsz;  // layer2, parity (T-1)&1=1
  for (int i = threadIdx.x; i < Hsz; i += 64) hs[i] = (float)hp[i];
  __syncthreads();
  int o = threadIdx.x;
  if (o < HORZ) {
    float a = fcb[o];
    #pragma unroll 8
    for (int u=0; u<Hsz; ++u) a += hs[u]*fcW[o*Hsz + u];
    out[b*HORZ + o] = a;
  }
}

extern "C" void kernel_launch(void* const* d_in, const int* in_sizes, int n_in,
                              void* d_out, int out_size, void* d_ws, size_t ws_size,
                              hipStream_t stream)
{
  const float* x     = (const float*)d_in[0];
  const float* Wih0  = (const float*)d_in[1];
  const float* Wih12 = (const float*)d_in[2];
  const float* Whh   = (const float*)d_in[3];
  const float* bih   = (const float*)d_in[4];
  const float* bhh   = (const float*)d_in[5];
  const float* fcW   = (const float*)d_in[6];
  const float* fcb   = (const float*)d_in[7];

  __bf16* hb = (__bf16*)d_ws;
  unsigned int* flags = (unsigned int*)((char*)d_ws + HBUF_ELEMS*2);
  size_t clr = HBUF_ELEMS*2 + (size_t)NFLAGS*4;
  hipMemsetAsync(d_ws, 0, clr, stream);   // zero h state + flags every call (replay-safe)

  hipLaunchKernelGGL(lstm_persist, dim3(3*NG*NBT), dim3(512), 0, stream,
                     x, Wih0, Wih12, Whh, bih, bhh, hb, flags);
  hipLaunchKernelGGL(fc_kernel, dim3(Bsz), dim3(64), 0, stream, hb, fcW, fcb, (float*)d_out);
}

// Round 2
// 8826.720 us; speedup vs baseline: 2.9195x; 2.9195x over previous
//
#include <hip/hip_runtime.h>
#include <hip/hip_bf16.h>
#include <stdint.h>

// Problem constants
#define Bsz 512
#define Tsz 512
#define Fsz 16
#define Hsz 256
#define HORZ 24

// Decomposition: 3 layers x NG gate-slices x NBT batch-tiles = 192 blocks
#define NG 8
#define NBT 8
#define BTILE 64
#define USL 32          // hidden units per slice
#define NCOL 128        // gate cols per block (USL*4 gates, interleaved unit*4+gate)
#define WROW_B 1024     // bytes per W LDS row (512 bf16)
#define WBYTES (NCOL*WROW_B)    // 128 KiB
#define HTILE_B (BTILE*USL*2)   // 4 KiB h-out coalescing tile
#define PD 2            // h parity depth
#define HBUF_ELEMS ((size_t)3*PD*Bsz*Hsz)
#define NFLAGS (3*NG*NBT)

typedef float  f32x4  __attribute__((ext_vector_type(4)));
typedef float  f32x16 __attribute__((ext_vector_type(16)));
typedef __bf16 bf16x8 __attribute__((ext_vector_type(8)));

__device__ __forceinline__ float sigm(float v){ return 1.f/(1.f+__expf(-v)); }
__device__ __forceinline__ float tanh_fast(float v){ return 1.f - 2.f/(1.f+__expf(2.f*v)); }

// K-chunk loop: A-frags straight from global (16B/lane/chunk), B-frags from LDS W.
// mfma_f32_32x32x16_bf16: A row=lane&31,k=(lane>>5)*8+j ; B col=lane&31,k=(lane>>5)*8+j.
template<int NCB, bool L0>
__device__ __forceinline__ void do_chunks(
    const __bf16* hinL, const __bf16* hrecL, const float* xpL,
    const char* wB, int swz, int kg8,
    f32x16& acc0, f32x16& acc1)
{
  auto fetchA = [&](int c) -> bf16x8 {
    if constexpr (L0) {
      if (c == 0) {                       // x chunk (16 f32 -> bf16)
        f32x4 a = *(const f32x4*)xpL;
        f32x4 b = *(const f32x4*)(xpL + 4);
        bf16x8 r;
        #pragma unroll
        for (int j=0;j<4;++j){ r[j]=(__bf16)a[j]; r[j+4]=(__bf16)b[j]; }
        return r;
      } else if (c <= 16) {               // recurrent h chunks
        return *(const bf16x8*)(hrecL + (c-1)*16);
      } else {                            // zero pad chunks 17..19
        bf16x8 z;
        #pragma unroll
        for (int j=0;j<8;++j) z[j]=(__bf16)0.f;
        return z;
      }
    } else {
      if (c < 16) return *(const bf16x8*)(hinL + c*16);       // x-part = h_{l-1,t}
      else        return *(const bf16x8*)(hrecL + (c-16)*16); // recurrent h_{l,t-1}
    }
  };
  auto readB = [&](int c) -> bf16x8 {
    int off = ((c*16 + kg8)*2) ^ swz;
    return *(const bf16x8*)(wB + off);
  };
  bf16x8 cur0=fetchA(0), cur1=fetchA(1), cur2=fetchA(2), cur3=fetchA(3);
  #pragma unroll
  for (int cb=0; cb<NCB; cb+=4){
    acc0 = __builtin_amdgcn_mfma_f32_32x32x16_bf16(cur0, readB(cb+0), acc0, 0,0,0);
    acc1 = __builtin_amdgcn_mfma_f32_32x32x16_bf16(cur1, readB(cb+1), acc1, 0,0,0);
    acc0 = __builtin_amdgcn_mfma_f32_32x32x16_bf16(cur2, readB(cb+2), acc0, 0,0,0);
    acc1 = __builtin_amdgcn_mfma_f32_32x32x16_bf16(cur3, readB(cb+3), acc1, 0,0,0);
    if (cb+4 < NCB){ cur0=fetchA(cb+4); cur1=fetchA(cb+5); cur2=fetchA(cb+6); cur3=fetchA(cb+7); }
  }
}

__global__ __launch_bounds__(512, 1) void lstm_persist(
    const float* __restrict__ xin,
    const float* __restrict__ Wih0,
    const float* __restrict__ Wih12,
    const float* __restrict__ Whh,
    const float* __restrict__ bih,
    const float* __restrict__ bhh,
    __bf16* __restrict__ hb,
    unsigned int* __restrict__ flags)
{
  __shared__ __align__(16) char smem[WBYTES + HTILE_B];   // 132 KiB -> 1 block/CU
  char* htile = smem + WBYTES;

  const int bid = blockIdx.x;
  const int l   = bid >> 6;
  const int g   = (bid >> 3) & 7;
  const int nb  = bid & 7;
  const int tid = threadIdx.x;
  const int lane = tid & 63;
  const int wid  = tid >> 6;          // 8 waves: 2M x 4N
  const int wm   = wid >> 2;
  const int wn   = wid & 3;
  const int b0   = nb * BTILE;
  const int m0   = wm * 32;
  const int n0   = wn * 32;

  // ---- one-time: W slice -> LDS [col][k 0..512), bf16, XOR-swizzled ----
  {
    const int col = tid >> 2;
    const int sub = tid & 3;
    const int R = (col&3)*Hsz + g*USL + (col>>2);
    for (int k0 = sub*8; k0 < 512; k0 += 32) {
      __bf16 tmp[8] __attribute__((aligned(16)));
      #pragma unroll
      for (int j=0;j<8;++j){
        int k = k0+j;
        float w;
        if (l==0){
          if (k < Fsz)           w = Wih0[R*Fsz + k];
          else if (k < 16+Hsz)   w = Whh[(size_t)R*Hsz + (k-16)];
          else                   w = 0.f;
        } else {
          if (k < Hsz) w = Wih12[((size_t)(l-1)*4*Hsz + R)*Hsz + k];
          else         w = Whh[((size_t)l*4*Hsz + R)*Hsz + (k-Hsz)];
        }
        tmp[j] = (__bf16)w;
      }
      int off = (k0*2) ^ ((col&7)<<4);
      *(bf16x8*)(smem + col*WROW_B + off) = *(bf16x8*)tmp;
    }
  }

  const int colL = n0 + (lane & 31);          // this lane's gate-col
  const int kg8  = (lane >> 5) * 8;
  const int swz  = (colL & 7) << 4;
  const char* wB = smem + colL*WROW_B;
  const int RL   = (colL&3)*Hsz + g*USL + (colL>>2);
  const float bias = bih[l*4*Hsz + RL] + bhh[l*4*Hsz + RL];
  const int rowA = m0 + (lane & 31);          // this lane's batch row in tile
  const size_t growA = (size_t)(b0 + rowA) * Hsz;

  float cst[16];
  #pragma unroll
  for (int i=0;i<16;++i) cst[i]=0.f;

  unsigned int* myflag = flags + ((l*NG+g)*NBT + nb);
  __syncthreads();

  for (int t=0; t<Tsz; ++t){
    // ---- point-to-point waits (threads 0..23, one flag each) ----
    {
      unsigned int* fp=nullptr; int target=0;
      int grp = tid>>3, gg = tid&7;
      if      (grp==0 && l>0)           { fp = flags + (((l-1)*NG+gg)*NBT+nb); target=t+1; }
      else if (grp==1 && t>0)           { fp = flags + ((l*NG+gg)*NBT+nb);     target=t;   }
      else if (grp==2 && l<2 && t>=PD)  { fp = flags + (((l+1)*NG+gg)*NBT+nb); target=t-(PD-1); }
      if (fp){
        int guard=0;
        while ((int)__hip_atomic_load(fp, __ATOMIC_RELAXED, __HIP_MEMORY_SCOPE_AGENT) < target){
          __builtin_amdgcn_s_sleep(1);
          if (++guard > (1<<22)) break;   // bailout: wrong answer instead of hang
        }
        (void)__hip_atomic_load(fp, __ATOMIC_ACQUIRE, __HIP_MEMORY_SCOPE_AGENT);  // buffer_inv
      }
      __syncthreads();
    }

    const __bf16* hinL  = (l>0) ? hb + ((size_t)((l-1)*PD + (t&(PD-1))))*Bsz*Hsz + growA + kg8
                                : (const __bf16*)nullptr;
    const __bf16* hrecL = hb + ((size_t)(l*PD + ((t+PD-1)&(PD-1))))*Bsz*Hsz + growA + kg8;
    __bf16*       hout  = hb + ((size_t)(l*PD + (t&(PD-1))))*Bsz*Hsz;
    const float*  xpL   = xin + ((size_t)(b0+rowA)*Tsz + t)*Fsz + kg8;

    f32x16 acc0, acc1;
    #pragma unroll
    for (int i=0;i<16;++i){ acc0[i]=0.f; acc1[i]=0.f; }

    if (l==0) do_chunks<20,true >(hinL, hrecL, xpL, wB, swz, kg8, acc0, acc1);
    else      do_chunks<32,false>(hinL, hrecL, xpL, wB, swz, kg8, acc0, acc1);

    // ---- epilogue: gather i,f,g,o from 4 neighbor lanes; f32 cell update ----
    #pragma unroll
    for (int i=0;i<16;++i){
      float v  = acc0[i] + acc1[i] + bias;
      float vf = __shfl_xor(v,1,64);
      float vg = __shfl_xor(v,2,64);
      float vo = __shfl_xor(v,3,64);
      float cn = sigm(vf)*cst[i] + sigm(v)*tanh_fast(vg);
      cst[i] = cn;
      float hv = sigm(vo)*tanh_fast(cn);
      if ((lane&3)==0){
        int r = (i&3) + 8*(i>>2) + 4*(lane>>5);   // C/D row map (32x32)
        int unit = colL >> 2;
        *(__bf16*)(htile + (m0 + r)*64 + unit*2) = (__bf16)hv;
      }
    }
    __syncthreads();

    // ---- coalesced h-out: packed u32 agent-scope stores (no dirty L2) ----
    {
      int row = tid>>3, q = tid&7;
      uint32_t v0 = *(const uint32_t*)(htile + row*64 + q*8);
      uint32_t v1 = *(const uint32_t*)(htile + row*64 + q*8 + 4);
      uint32_t* dst = (uint32_t*)(hout + (size_t)(b0+row)*Hsz + g*USL + q*4);
      __hip_atomic_store(dst,   v0, __ATOMIC_RELAXED, __HIP_MEMORY_SCOPE_AGENT);
      __hip_atomic_store(dst+1, v1, __ATOMIC_RELAXED, __HIP_MEMORY_SCOPE_AGENT);
    }
    __syncthreads();   // drains each thread's stores (vmcnt0) before release
    if (tid==0)
      __hip_atomic_store(myflag, (unsigned int)(t+1), __ATOMIC_RELEASE, __HIP_MEMORY_SCOPE_AGENT);
  }
}

__global__ void fc_kernel(const __bf16* __restrict__ hb,
                          const float* __restrict__ fcW,
                          const float* __restrict__ fcb,
                          float* __restrict__ out)
{
  __shared__ float hs[Hsz];
  int b = blockIdx.x;
  const __bf16* hp = hb + ((size_t)(2*PD + ((Tsz-1)&(PD-1))))*Bsz*Hsz + (size_t)b*Hsz;
  for (int i = threadIdx.x; i < Hsz; i += 64) hs[i] = (float)hp[i];
  __syncthreads();
  int o = threadIdx.x;
  if (o < HORZ) {
    float a = fcb[o];
    #pragma unroll 8
    for (int u=0; u<Hsz; ++u) a += hs[u]*fcW[o*Hsz + u];
    out[b*HORZ + o] = a;
  }
}

extern "C" void kernel_launch(void* const* d_in, const int* in_sizes, int n_in,
                              void* d_out, int out_size, void* d_ws, size_t ws_size,
                              hipStream_t stream)
{
  const float* x     = (const float*)d_in[0];
  const float* Wih0  = (const float*)d_in[1];
  const float* Wih12 = (const float*)d_in[2];
  const float* Whh   = (const float*)d_in[3];
  const float* bih   = (const float*)d_in[4];
  const float* bhh   = (const float*)d_in[5];
  const float* fcW   = (const float*)d_in[6];
  const float* fcb   = (const float*)d_in[7];

  __bf16* hb = (__bf16*)d_ws;
  unsigned int* flags = (unsigned int*)((char*)d_ws + HBUF_ELEMS*2);
  size_t clr = HBUF_ELEMS*2 + (size_t)NFLAGS*4;
  hipMemsetAsync(d_ws, 0, clr, stream);   // zero h state + flags (replay-safe)

  hipLaunchKernelGGL(lstm_persist, dim3(3*NG*NBT), dim3(512), 0, stream,
                     x, Wih0, Wih12, Whh, bih, bhh, hb, flags);
  hipLaunchKernelGGL(fc_kernel, dim3(Bsz), dim3(64), 0, stream, hb, fcW, fcb, (float*)d_out);
}

// Round 3
// 6658.920 us; speedup vs baseline: 3.8699x; 1.3255x over previous
//
#include <hip/hip_runtime.h>
#include <hip/hip_bf16.h>
#include <stdint.h>

// Problem constants
#define Bsz 512
#define Tsz 512
#define Fsz 16
#define Hsz 256
#define HORZ 24

// Decomposition: 3 layers x NG gate-slices x NBT batch-tiles = 192 blocks
#define NG 8
#define NBT 8
#define BTILE 64
#define USL 32          // hidden units per slice
#define NCOL 128        // gate cols per block
#define PD 4            // h parity depth (power of 2); inv every 2 steps covers reuse
#define HBUF_ELEMS ((size_t)3*PD*Bsz*Hsz)
#define NFLAGS (3*NG*NBT)
#define HTILE_B (BTILE*USL*2)   // 4 KiB

typedef float  f32x4  __attribute__((ext_vector_type(4)));
typedef float  f32x16 __attribute__((ext_vector_type(16)));
typedef __bf16 bf16x8 __attribute__((ext_vector_type(8)));

__device__ __forceinline__ float sigm(float v){ return 1.f/(1.f+__expf(-v)); }

// L1-bypass, L2-cached 16B load (freshness guaranteed by periodic buffer_inv)
__device__ __forceinline__ bf16x8 ld_sc0_b128(const void* p){
  bf16x8 r;
  asm volatile("global_load_dwordx4 %0, %1, off sc0"
    : "=&v"(r) : "v"(p) : "memory");
  return r;
}
// L1+L2-bypass ops: coherent at Infinity Cache, no wbl2/inv needed
__device__ __forceinline__ void st_sc01_b64(void* p, uint64_t v){
  asm volatile("global_store_dwordx2 %0, %1, off sc0 sc1"
    :: "v"(p), "v"(v) : "memory");
}
__device__ __forceinline__ void st_sc01_b32(void* p, uint32_t v){
  asm volatile("global_store_dword %0, %1, off sc0 sc1"
    :: "v"(p), "v"(v) : "memory");
}
__device__ __forceinline__ uint32_t ld_sc01_b32(const void* p){
  uint32_t r;
  asm volatile("global_load_dword %0, %1, off sc0 sc1\n\ts_waitcnt vmcnt(0)"
    : "=&v"(r) : "v"(p) : "memory");
  return r;
}

template<bool L0>
__device__ __forceinline__ void lstm_body(
    int l, int g, int nb, int tid,
    const float* __restrict__ xin,
    const float* __restrict__ Wih0,
    const float* __restrict__ Wih12,
    const float* __restrict__ Whh,
    const float* __restrict__ bih,
    const float* __restrict__ bhh,
    __bf16* __restrict__ hb,
    unsigned int* __restrict__ flags,
    char* htile)
{
  const int lane = tid & 63;
  const int wid  = tid >> 6;          // 8 waves: 2M x 4N
  const int wm   = wid >> 2;
  const int wn   = wid & 3;
  const int b0   = nb * BTILE;
  const int m0   = wm * 32;
  const int n0   = wn * 32;

  const int colL = n0 + (lane & 31);            // this lane's gate-col (0..127)
  const int kg8  = (lane >> 5) * 8;             // k-group offset (0 or 8)
  const int R    = (colL&3)*Hsz + g*USL + (colL>>2);   // weight row
  const float bias = bih[l*4*Hsz + R] + bhh[l*4*Hsz + R];
  const int rowA = m0 + (lane & 31);            // batch row within tile
  const size_t growA = (size_t)(b0 + rowA) * Hsz;

  // ---- one-time: W fragments -> REGISTERS (persistent all 512 steps) ----
  constexpr int NC = L0 ? 17 : 32;
  bf16x8 w[NC];
  {
    const float* recB = Whh + ((size_t)l*4*Hsz + R)*Hsz;
    if constexpr (L0) {
      const float* xB = Wih0 + (size_t)R*Fsz;
      #pragma unroll
      for (int c=0;c<17;++c){
        const float* p = (c==0) ? (xB + kg8) : (recB + (c-1)*16 + kg8);
        f32x4 u0 = *(const f32x4*)p;
        f32x4 u1 = *(const f32x4*)(p+4);
        bf16x8 t;
        #pragma unroll
        for (int j=0;j<4;++j){ t[j]=(__bf16)u0[j]; t[j+4]=(__bf16)u1[j]; }
        w[c] = t;
      }
    } else {
      const float* ihB = Wih12 + ((size_t)(l-1)*4*Hsz + R)*Hsz;
      #pragma unroll
      for (int c=0;c<32;++c){
        const float* p = (c<16) ? (ihB + c*16 + kg8) : (recB + (c-16)*16 + kg8);
        f32x4 u0 = *(const f32x4*)p;
        f32x4 u1 = *(const f32x4*)(p+4);
        bf16x8 t;
        #pragma unroll
        for (int j=0;j<4;++j){ t[j]=(__bf16)u0[j]; t[j+4]=(__bf16)u1[j]; }
        w[c] = t;
      }
    }
  }

  float cst[16];
  #pragma unroll
  for (int i=0;i<16;++i) cst[i]=0.f;

  unsigned int* myflag = flags + ((l*NG+g)*NBT + nb);
  const bool q2 = ((colL & 3) == 2);
  __syncthreads();

  for (int t=0; t<Tsz; ++t){
    // ---- point-to-point waits (threads 0..23, one flag each) + periodic inv ----
    {
      unsigned int* fp=nullptr; int target=0;
      int grp = tid>>3, gg = tid&7;
      if      (grp==0 && l>0)           { fp = flags + (((l-1)*NG+gg)*NBT+nb); target=t+1; }
      else if (grp==1 && t>0)           { fp = flags + ((l*NG+gg)*NBT+nb);     target=t;   }
      else if (grp==2 && l<2 && t>=PD)  { fp = flags + (((l+1)*NG+gg)*NBT+nb); target=t-(PD-1); }
      if (fp){
        int guard=0;
        while ((int)ld_sc01_b32(fp) < target){
          __builtin_amdgcn_s_sleep(1);
          if (++guard > (1<<22)) break;   // bailout: wrong answer instead of hang
        }
      }
      if (((t & 1) == 0) && tid == 0) {
        // acquire => buffer_inv: flush L2 so sc0 loads refetch fresh IC data.
        (void)__hip_atomic_load(myflag, __ATOMIC_ACQUIRE, __HIP_MEMORY_SCOPE_AGENT);
      }
      __syncthreads();
    }

    const __bf16* hinL  = hb + ((size_t)((l-1)*PD + (t&(PD-1))))*Bsz*Hsz + growA + kg8;
    const __bf16* hrecL = hb + ((size_t)(l*PD + ((t+PD-1)&(PD-1))))*Bsz*Hsz + growA + kg8;
    __bf16*       hout  = hb + ((size_t)(l*PD + (t&(PD-1))))*Bsz*Hsz;

    f32x16 acc;
    #pragma unroll
    for (int i=0;i<16;++i) acc[i]=0.f;

    if constexpr (L0) {
      bf16x8 a[17];
      {  // x chunk: 16 f32 (plain cached loads; x is read-only)
        const float* xp = xin + ((size_t)(b0+rowA)*Tsz + t)*Fsz + kg8;
        f32x4 u0 = *(const f32x4*)xp;
        f32x4 u1 = *(const f32x4*)(xp+4);
        bf16x8 tx;
        #pragma unroll
        for (int j=0;j<4;++j){ tx[j]=(__bf16)u0[j]; tx[j+4]=(__bf16)u1[j]; }
        a[0] = tx;
      }
      #pragma unroll
      for (int c=1;c<17;++c) a[c] = ld_sc0_b128(hrecL + (c-1)*16);
      asm volatile("s_waitcnt vmcnt(0)" ::: "memory");
      __builtin_amdgcn_sched_barrier(0);
      #pragma unroll
      for (int c=0;c<17;++c)
        acc = __builtin_amdgcn_mfma_f32_32x32x16_bf16(a[c], w[c], acc, 0,0,0);
    } else {
      bf16x8 a[16];
      #pragma unroll
      for (int c=0;c<16;++c) a[c] = ld_sc0_b128(hinL + c*16);
      asm volatile("s_waitcnt vmcnt(0)" ::: "memory");
      __builtin_amdgcn_sched_barrier(0);
      #pragma unroll
      for (int c=0;c<16;++c)
        acc = __builtin_amdgcn_mfma_f32_32x32x16_bf16(a[c], w[c], acc, 0,0,0);
      #pragma unroll
      for (int c=0;c<16;++c) a[c] = ld_sc0_b128(hrecL + c*16);
      asm volatile("s_waitcnt vmcnt(0)" ::: "memory");
      __builtin_amdgcn_sched_barrier(0);
      #pragma unroll
      for (int c=0;c<16;++c)
        acc = __builtin_amdgcn_mfma_f32_32x32x16_bf16(a[c], w[c+16], acc, 0,0,0);
    }

    // ---- epilogue: 1 transcendental/lane/row; gather gates via shfl ----
    #pragma unroll
    for (int i=0;i<16;++i){
      float v  = acc[i] + bias;
      float vv = q2 ? 2.f*v : v;
      float s  = sigm(vv);
      float act = q2 ? (2.f*s - 1.f) : s;   // tanh for g-gate, sigmoid otherwise
      float a1 = __shfl_xor(act,1,64);      // f (sigm)
      float a2 = __shfl_xor(act,2,64);      // g (tanh)
      float a3 = __shfl_xor(act,3,64);      // o (sigm)
      if ((lane&3)==0){
        float cn = a1*cst[i] + act*a2;
        cst[i] = cn;
        float th = 2.f*sigm(2.f*cn) - 1.f;  // tanh(cn)
        float hv = a3*th;
        int r = (i&3) + 8*(i>>2) + 4*(lane>>5);   // 32x32 C/D row map
        int unit = colL >> 2;
        *(__bf16*)(htile + (m0 + r)*64 + unit*2) = (__bf16)hv;
      }
    }
    __syncthreads();

    // ---- coalesced h-out: 8B/thread, L2-bypass stores to IC ----
    {
      int row = tid>>3, q = tid&7;
      uint64_t v = *(const uint64_t*)(htile + row*64 + q*8);
      st_sc01_b64(hout + (size_t)(b0+row)*Hsz + g*USL + q*4, v);
    }
    asm volatile("s_waitcnt vmcnt(0)" ::: "memory");   // stores visible at IC
    __syncthreads();
    if (tid==0) st_sc01_b32(myflag, (uint32_t)(t+1));
  }
}

__global__ __launch_bounds__(512, 2) void lstm_persist(
    const float* __restrict__ xin,
    const float* __restrict__ Wih0,
    const float* __restrict__ Wih12,
    const float* __restrict__ Whh,
    const float* __restrict__ bih,
    const float* __restrict__ bhh,
    __bf16* __restrict__ hb,
    unsigned int* __restrict__ flags)
{
  __shared__ __align__(16) char htile[HTILE_B];
  const int bid = blockIdx.x;
  const int l   = bid >> 6;
  const int g   = (bid >> 3) & 7;
  const int nb  = bid & 7;
  const int tid = threadIdx.x;
  if (l == 0)
    lstm_body<true >(l,g,nb,tid, xin,Wih0,Wih12,Whh,bih,bhh, hb,flags, htile);
  else
    lstm_body<false>(l,g,nb,tid, xin,Wih0,Wih12,Whh,bih,bhh, hb,flags, htile);
}

__global__ void fc_kernel(const __bf16* __restrict__ hb,
                          const float* __restrict__ fcW,
                          const float* __restrict__ fcb,
                          float* __restrict__ out)
{
  __shared__ float hs[Hsz];
  int b = blockIdx.x;
  const __bf16* hp = hb + ((size_t)(2*PD + ((Tsz-1)&(PD-1))))*Bsz*Hsz + (size_t)b*Hsz;
  for (int i = threadIdx.x; i < Hsz; i += 64) hs[i] = (float)hp[i];
  __syncthreads();
  int o = threadIdx.x;
  if (o < HORZ) {
    float a = fcb[o];
    #pragma unroll 8
    for (int u=0; u<Hsz; ++u) a += hs[u]*fcW[o*Hsz + u];
    out[b*HORZ + o] = a;
  }
}

extern "C" void kernel_launch(void* const* d_in, const int* in_sizes, int n_in,
                              void* d_out, int out_size, void* d_ws, size_t ws_size,
                              hipStream_t stream)
{
  const float* x     = (const float*)d_in[0];
  const float* Wih0  = (const float*)d_in[1];
  const float* Wih12 = (const float*)d_in[2];
  const float* Whh   = (const float*)d_in[3];
  const float* bih   = (const float*)d_in[4];
  const float* bhh   = (const float*)d_in[5];
  const float* fcW   = (const float*)d_in[6];
  const float* fcb   = (const float*)d_in[7];

  __bf16* hb = (__bf16*)d_ws;
  unsigned int* flags = (unsigned int*)((char*)d_ws + HBUF_ELEMS*2);
  size_t clr = HBUF_ELEMS*2 + (size_t)NFLAGS*4;
  hipMemsetAsync(d_ws, 0, clr, stream);   // zero h state + flags (replay-safe)

  hipLaunchKernelGGL(lstm_persist, dim3(3*NG*NBT), dim3(512), 0, stream,
                     x, Wih0, Wih12, Whh, bih, bhh, hb, flags);
  hipLaunchKernelGGL(fc_kernel, dim3(Bsz), dim3(64), 0, stream, hb, fcW, fcb, (float*)d_out);
}

// Round 4
// 6220.525 us; speedup vs baseline: 4.1427x; 1.0705x over previous
//
#include <hip/hip_runtime.h>
#include <hip/hip_bf16.h>
#include <stdint.h>

// Problem constants
#define Bsz 512
#define Tsz 512
#define Fsz 16
#define Hsz 256
#define HORZ 24

// Decomposition: 3 layers x NG gate-slices x NBT batch-tiles = 192 blocks
#define NG 8
#define NBT 8
#define BTILE 64
#define USL 32          // hidden units per slice
#define PD 4            // h parity depth (power of 2)
#define HBUF_ELEMS ((size_t)3*PD*Bsz*Hsz)
#define NFLAGS (3*NG*NBT)
#define HTILE_B (BTILE*USL*2)   // 4 KiB

typedef float  f32x4  __attribute__((ext_vector_type(4)));
typedef float  f32x16 __attribute__((ext_vector_type(16)));
typedef __bf16 bf16x8 __attribute__((ext_vector_type(8)));

__device__ __forceinline__ float sigm(float v){ return 1.f/(1.f+__expf(-v)); }

// ---- L1+L2-bypass ops: coherent at the memory-side Infinity Cache.
// No buffer_inv / buffer_wbl2 anywhere in the kernel. Round-3 verified that
// sc01 loads observe remote sc01 stores (flag protocol ran on exactly this).
__device__ __forceinline__ bf16x8 ld_sc01_b128(const void* p){
  bf16x8 r;
  asm volatile("global_load_dwordx4 %0, %1, off sc0 sc1"
    : "=&v"(r) : "v"(p) : "memory");
  return r;
}
__device__ __forceinline__ void st_sc01_b64(void* p, uint64_t v){
  asm volatile("global_store_dwordx2 %0, %1, off sc0 sc1"
    :: "v"(p), "v"(v) : "memory");
}
__device__ __forceinline__ void st_sc01_b32(void* p, uint32_t v){
  asm volatile("global_store_dword %0, %1, off sc0 sc1"
    :: "v"(p), "v"(v) : "memory");
}
__device__ __forceinline__ uint32_t ld_sc01_b32(const void* p){
  uint32_t r;
  asm volatile("global_load_dword %0, %1, off sc0 sc1\n\ts_waitcnt vmcnt(0)"
    : "=&v"(r) : "v"(p) : "memory");
  return r;
}

template<bool L0>
__device__ __forceinline__ void lstm_body(
    int l, int g, int nb, int tid,
    const float* __restrict__ xin,
    const float* __restrict__ Wih0,
    const float* __restrict__ Wih12,
    const float* __restrict__ Whh,
    const float* __restrict__ bih,
    const float* __restrict__ bhh,
    __bf16* __restrict__ hb,
    unsigned int* __restrict__ flags,
    char* htile)
{
  const int lane = tid & 63;
  const int wid  = tid >> 6;          // 8 waves: 2M x 4N
  const int wm   = wid >> 2;
  const int wn   = wid & 3;
  const int b0   = nb * BTILE;
  const int m0   = wm * 32;
  const int n0   = wn * 32;

  const int colL = n0 + (lane & 31);            // this lane's gate-col (0..127)
  const int kg8  = (lane >> 5) * 8;             // k-group offset (0 or 8)
  const int R    = (colL&3)*Hsz + g*USL + (colL>>2);   // weight row
  const float bias = bih[l*4*Hsz + R] + bhh[l*4*Hsz + R];
  const int rowA = m0 + (lane & 31);            // batch row within tile
  const size_t growA = (size_t)(b0 + rowA) * Hsz;

  // ---- one-time: W fragments -> registers/AGPRs (persistent all 512 steps) ----
  constexpr int NC = L0 ? 17 : 32;
  bf16x8 w[NC];
  {
    const float* recB = Whh + ((size_t)l*4*Hsz + R)*Hsz;
    if constexpr (L0) {
      const float* xB = Wih0 + (size_t)R*Fsz;
      #pragma unroll
      for (int c=0;c<17;++c){
        const float* p = (c==0) ? (xB + kg8) : (recB + (c-1)*16 + kg8);
        f32x4 u0 = *(const f32x4*)p;
        f32x4 u1 = *(const f32x4*)(p+4);
        bf16x8 t;
        #pragma unroll
        for (int j=0;j<4;++j){ t[j]=(__bf16)u0[j]; t[j+4]=(__bf16)u1[j]; }
        w[c] = t;
      }
    } else {
      const float* ihB = Wih12 + ((size_t)(l-1)*4*Hsz + R)*Hsz;
      #pragma unroll
      for (int c=0;c<32;++c){
        const float* p = (c<16) ? (ihB + c*16 + kg8) : (recB + (c-16)*16 + kg8);
        f32x4 u0 = *(const f32x4*)p;
        f32x4 u1 = *(const f32x4*)(p+4);
        bf16x8 t;
        #pragma unroll
        for (int j=0;j<4;++j){ t[j]=(__bf16)u0[j]; t[j+4]=(__bf16)u1[j]; }
        w[c] = t;
      }
    }
  }

  float cst[16];
  #pragma unroll
  for (int i=0;i<16;++i) cst[i]=0.f;

  unsigned int* myflag = flags + ((l*NG+g)*NBT + nb);
  const bool q2 = ((colL & 3) == 2);
  __syncthreads();

  for (int t=0; t<Tsz; ++t){
    // ---- point-to-point waits (threads 0..23, one flag each); no cache ops ----
    {
      unsigned int* fp=nullptr; int target=0;
      int grp = tid>>3, gg = tid&7;
      if      (grp==0 && l>0)           { fp = flags + (((l-1)*NG+gg)*NBT+nb); target=t+1; }
      else if (grp==1 && t>0)           { fp = flags + ((l*NG+gg)*NBT+nb);     target=t;   }
      else if (grp==2 && l<2 && t>=PD)  { fp = flags + (((l+1)*NG+gg)*NBT+nb); target=t-(PD-1); }
      if (fp){
        int guard=0;
        while ((int)ld_sc01_b32(fp) < target){
          __builtin_amdgcn_s_sleep(1);
          if (++guard > (1<<22)) break;   // bailout: wrong answer instead of hang
        }
      }
      __syncthreads();
    }

    const __bf16* hinL  = hb + ((size_t)((l-1)*PD + (t&(PD-1))))*Bsz*Hsz + growA + kg8;
    const __bf16* hrecL = hb + ((size_t)(l*PD + ((t+PD-1)&(PD-1))))*Bsz*Hsz + growA + kg8;
    __bf16*       hout  = hb + ((size_t)(l*PD + (t&(PD-1))))*Bsz*Hsz;

    f32x16 acc;
    #pragma unroll
    for (int i=0;i<16;++i) acc[i]=0.f;

    if constexpr (L0) {
      bf16x8 a[17];
      {  // x chunk: 16 f32 (plain cached loads; x is read-only so L1/L2 safe)
        const float* xp = xin + ((size_t)(b0+rowA)*Tsz + t)*Fsz + kg8;
        f32x4 u0 = *(const f32x4*)xp;
        f32x4 u1 = *(const f32x4*)(xp+4);
        bf16x8 tx;
        #pragma unroll
        for (int j=0;j<4;++j){ tx[j]=(__bf16)u0[j]; tx[j+4]=(__bf16)u1[j]; }
        a[0] = tx;
      }
      #pragma unroll
      for (int c=1;c<17;++c) a[c] = ld_sc01_b128(hrecL + (c-1)*16);
      asm volatile("s_waitcnt vmcnt(0)" ::: "memory");
      __builtin_amdgcn_sched_barrier(0);
      #pragma unroll
      for (int c=0;c<17;++c)
        acc = __builtin_amdgcn_mfma_f32_32x32x16_bf16(a[c], w[c], acc, 0,0,0);
    } else {
      bf16x8 a[16];
      #pragma unroll
      for (int c=0;c<16;++c) a[c] = ld_sc01_b128(hinL + c*16);
      asm volatile("s_waitcnt vmcnt(0)" ::: "memory");
      __builtin_amdgcn_sched_barrier(0);
      #pragma unroll
      for (int c=0;c<16;++c)
        acc = __builtin_amdgcn_mfma_f32_32x32x16_bf16(a[c], w[c], acc, 0,0,0);
      #pragma unroll
      for (int c=0;c<16;++c) a[c] = ld_sc01_b128(hrecL + c*16);
      asm volatile("s_waitcnt vmcnt(0)" ::: "memory");
      __builtin_amdgcn_sched_barrier(0);
      #pragma unroll
      for (int c=0;c<16;++c)
        acc = __builtin_amdgcn_mfma_f32_32x32x16_bf16(a[c], w[c+16], acc, 0,0,0);
    }

    // ---- epilogue: 1 transcendental/lane/row; gather gates via shfl ----
    #pragma unroll
    for (int i=0;i<16;++i){
      float v  = acc[i] + bias;
      float vv = q2 ? 2.f*v : v;
      float s  = sigm(vv);
      float act = q2 ? (2.f*s - 1.f) : s;   // tanh for g-gate, sigmoid otherwise
      float a1 = __shfl_xor(act,1,64);      // f (sigm)
      float a2 = __shfl_xor(act,2,64);      // g (tanh)
      float a3 = __shfl_xor(act,3,64);      // o (sigm)
      if ((lane&3)==0){
        float cn = a1*cst[i] + act*a2;
        cst[i] = cn;
        float th = 2.f*sigm(2.f*cn) - 1.f;  // tanh(cn)
        float hv = a3*th;
        int r = (i&3) + 8*(i>>2) + 4*(lane>>5);   // 32x32 C/D row map
        int unit = colL >> 2;
        *(__bf16*)(htile + (m0 + r)*64 + unit*2) = (__bf16)hv;
      }
    }
    __syncthreads();

    // ---- coalesced h-out: 8B/thread, IC-coherent stores ----
    {
      int row = tid>>3, q = tid&7;
      uint64_t v = *(const uint64_t*)(htile + row*64 + q*8);
      st_sc01_b64(hout + (size_t)(b0+row)*Hsz + g*USL + q*4, v);
    }
    asm volatile("s_waitcnt vmcnt(0)" ::: "memory");   // own stores visible at IC
    __syncthreads();                                    // => all block's stores done
    if (tid==0) st_sc01_b32(myflag, (uint32_t)(t+1));
  }
}

__global__ __launch_bounds__(512, 2) void lstm_persist(
    const float* __restrict__ xin,
    const float* __restrict__ Wih0,
    const float* __restrict__ Wih12,
    const float* __restrict__ Whh,
    const float* __restrict__ bih,
    const float* __restrict__ bhh,
    __bf16* __restrict__ hb,
    unsigned int* __restrict__ flags)
{
  __shared__ __align__(16) char htile[HTILE_B];
  const int bid = blockIdx.x;
  const int l   = bid >> 6;
  const int g   = (bid >> 3) & 7;
  const int nb  = bid & 7;
  const int tid = threadIdx.x;
  if (l == 0)
    lstm_body<true >(l,g,nb,tid, xin,Wih0,Wih12,Whh,bih,bhh, hb,flags, htile);
  else
    lstm_body<false>(l,g,nb,tid, xin,Wih0,Wih12,Whh,bih,bhh, hb,flags, htile);
}

__global__ void fc_kernel(const __bf16* __restrict__ hb,
                          const float* __restrict__ fcW,
                          const float* __restrict__ fcb,
                          float* __restrict__ out)
{
  __shared__ float hs[Hsz];
  int b = blockIdx.x;
  const __bf16* hp = hb + ((size_t)(2*PD + ((Tsz-1)&(PD-1))))*Bsz*Hsz + (size_t)b*Hsz;
  for (int i = threadIdx.x; i < Hsz; i += 64) hs[i] = (float)hp[i];
  __syncthreads();
  int o = threadIdx.x;
  if (o < HORZ) {
    float a = fcb[o];
    #pragma unroll 8
    for (int u=0; u<Hsz; ++u) a += hs[u]*fcW[o*Hsz + u];
    out[b*HORZ + o] = a;
  }
}

extern "C" void kernel_launch(void* const* d_in, const int* in_sizes, int n_in,
                              void* d_out, int out_size, void* d_ws, size_t ws_size,
                              hipStream_t stream)
{
  const float* x     = (const float*)d_in[0];
  const float* Wih0  = (const float*)d_in[1];
  const float* Wih12 = (const float*)d_in[2];
  const float* Whh   = (const float*)d_in[3];
  const float* bih   = (const float*)d_in[4];
  const float* bhh   = (const float*)d_in[5];
  const float* fcW   = (const float*)d_in[6];
  const float* fcb   = (const float*)d_in[7];

  __bf16* hb = (__bf16*)d_ws;
  unsigned int* flags = (unsigned int*)((char*)d_ws + HBUF_ELEMS*2);
  size_t clr = HBUF_ELEMS*2 + (size_t)NFLAGS*4;
  hipMemsetAsync(d_ws, 0, clr, stream);   // zero h state + flags (replay-safe)

  hipLaunchKernelGGL(lstm_persist, dim3(3*NG*NBT), dim3(512), 0, stream,
                     x, Wih0, Wih12, Whh, bih, bhh, hb, flags);
  hipLaunchKernelGGL(fc_kernel, dim3(Bsz), dim3(64), 0, stream, hb, fcW, fcb, (float*)d_out);
}

// Round 5
// 6043.560 us; speedup vs baseline: 4.2640x; 1.0293x over previous
//
#include <hip/hip_runtime.h>
#include <hip/hip_bf16.h>
#include <stdint.h>

// Problem constants
#define Bsz 512
#define Tsz 512
#define Fsz 16
#define Hsz 256
#define HORZ 24

// Decomposition: 3 layers x NG gate-slices x NBT batch-tiles = 192 blocks
#define NG 8
#define NBT 8
#define BTILE 64
#define USL 32          // hidden units per slice
#define PD 4            // h parity depth (power of 2)
#define HBUF_ELEMS ((size_t)3*PD*Bsz*Hsz)
#define NFLAGS (3*NG*NBT)
#define WROW_B 1024                 // 1 KiB per gate-col (512 k * bf16)
#define WBYTES (128*WROW_B)         // 128 KiB
#define HTILE_B (BTILE*USL*2)       // 4 KiB

typedef float  f32x4  __attribute__((ext_vector_type(4)));
typedef float  f32x16 __attribute__((ext_vector_type(16)));
typedef __bf16 bf16x8 __attribute__((ext_vector_type(8)));

__device__ __forceinline__ float sigm(float v){ return 1.f/(1.f+__expf(-v)); }

// ---- L1+L2-bypass ops: coherent at the memory-side Infinity Cache.
__device__ __forceinline__ bf16x8 ld_sc01_b128(const void* p){
  bf16x8 r;
  asm volatile("global_load_dwordx4 %0, %1, off sc0 sc1"
    : "=&v"(r) : "v"(p) : "memory");
  return r;
}
__device__ __forceinline__ void st_sc01_b64(void* p, uint64_t v){
  asm volatile("global_store_dwordx2 %0, %1, off sc0 sc1"
    :: "v"(p), "v"(v) : "memory");
}
__device__ __forceinline__ void st_sc01_b32(void* p, uint32_t v){
  asm volatile("global_store_dword %0, %1, off sc0 sc1"
    :: "v"(p), "v"(v) : "memory");
}
__device__ __forceinline__ uint32_t ld_sc01_b32(const void* p){
  uint32_t r;
  asm volatile("global_load_dword %0, %1, off sc0 sc1\n\ts_waitcnt vmcnt(0)"
    : "=&v"(r) : "v"(p) : "memory");
  return r;
}

template<bool L0>
__device__ __forceinline__ void lstm_body(
    int l, int g, int nb, int tid,
    const float* __restrict__ xin,
    const float* __restrict__ Wih0,
    const float* __restrict__ Wih12,
    const float* __restrict__ Whh,
    const float* __restrict__ bih,
    const float* __restrict__ bhh,
    __bf16* __restrict__ hb,
    unsigned int* __restrict__ flags,
    char* wlds, char* htile)
{
  const int lane = tid & 63;
  const int wid  = tid >> 6;          // 8 waves: 2M x 4N
  const int wm   = wid >> 2;
  const int wn   = wid & 3;
  const int b0   = nb * BTILE;
  const int m0   = wm * 32;
  const int n0   = wn * 32;

  constexpr int NC = L0 ? 17 : 32;    // K chunks of 16

  // ---- one-time: W slice -> LDS [col][k], bf16, XOR-swizzled 16B slots ----
  {
    const int col = tid >> 2;         // 0..127
    const int sub = tid & 3;
    const int R = (col&3)*Hsz + g*USL + (col>>2);
    const int swzc = (col&7)<<4;
    for (int c = sub; c < NC; c += 4) {
      const float* src;
      if constexpr (L0) {
        src = (c==0) ? (Wih0 + (size_t)R*Fsz)
                     : (Whh + ((size_t)l*4*Hsz + R)*Hsz + (c-1)*16);
      } else {
        src = (c<16) ? (Wih12 + ((size_t)(l-1)*4*Hsz + R)*Hsz + c*16)
                     : (Whh + ((size_t)l*4*Hsz + R)*Hsz + (c-16)*16);
      }
      __bf16 tb[16] __attribute__((aligned(16)));
      #pragma unroll
      for (int j=0;j<16;++j) tb[j] = (__bf16)src[j];
      *(bf16x8*)(wlds + col*WROW_B + ((c*32)    ^ swzc)) = *(bf16x8*)(tb);
      *(bf16x8*)(wlds + col*WROW_B + ((c*32+16) ^ swzc)) = *(bf16x8*)(tb+8);
    }
  }

  const int colL = n0 + (lane & 31);            // this lane's gate-col (0..127)
  const int kg8  = (lane >> 5) * 8;             // k offset within chunk (0 or 8)
  const int kg16 = (lane >> 5) * 16;            // byte offset within chunk
  const int swz  = (colL & 7) << 4;
  const char* wcol = wlds + colL*WROW_B;
  const int R    = (colL&3)*Hsz + g*USL + (colL>>2);
  const float bias = bih[l*4*Hsz + R] + bhh[l*4*Hsz + R];
  const int rowA = m0 + (lane & 31);            // batch row within tile
  const size_t growA = (size_t)(b0 + rowA) * Hsz;

  float cst[16];
  #pragma unroll
  for (int i=0;i<16;++i) cst[i]=0.f;

  unsigned int* myflag = flags + ((l*NG+g)*NBT + nb);
  const bool q2 = ((colL & 3) == 2);
  __syncthreads();

  for (int t=0; t<Tsz; ++t){
    // ---- point-to-point waits (threads 0..23, one flag each); no cache ops ----
    {
      unsigned int* fp=nullptr; int target=0;
      int grp = tid>>3, gg = tid&7;
      if      (grp==0 && l>0)           { fp = flags + (((l-1)*NG+gg)*NBT+nb); target=t+1; }
      else if (grp==1 && t>0)           { fp = flags + ((l*NG+gg)*NBT+nb);     target=t;   }
      else if (grp==2 && l<2 && t>=PD)  { fp = flags + (((l+1)*NG+gg)*NBT+nb); target=t-(PD-1); }
      if (fp){
        int guard=0;
        while ((int)ld_sc01_b32(fp) < target){
          __builtin_amdgcn_s_sleep(1);
          if (++guard > (1<<22)) break;   // bailout: wrong answer instead of hang
        }
      }
      __syncthreads();
    }

    const __bf16* hinL  = hb + ((size_t)((l-1)*PD + (t&(PD-1))))*Bsz*Hsz + growA + kg8;
    const __bf16* hrecL = hb + ((size_t)(l*PD + ((t+PD-1)&(PD-1))))*Bsz*Hsz + growA + kg8;
    __bf16*       hout  = hb + ((size_t)(l*PD + (t&(PD-1))))*Bsz*Hsz;

    // ---- single merged A-load phase: ONE IC round trip for all 32 chunks ----
    bf16x8 a[NC];
    if constexpr (L0) {
      {  // x chunk: 16 f32 (read-only; plain cached loads)
        const float* xp = xin + ((size_t)(b0+rowA)*Tsz + t)*Fsz + kg8;
        f32x4 u0 = *(const f32x4*)xp;
        f32x4 u1 = *(const f32x4*)(xp+4);
        bf16x8 tx;
        #pragma unroll
        for (int j=0;j<4;++j){ tx[j]=(__bf16)u0[j]; tx[j+4]=(__bf16)u1[j]; }
        a[0] = tx;
      }
      #pragma unroll
      for (int c=1;c<17;++c) a[c] = ld_sc01_b128(hrecL + (c-1)*16);
    } else {
      #pragma unroll
      for (int c=0;c<16;++c)  a[c] = ld_sc01_b128(hinL + c*16);
      #pragma unroll
      for (int c=16;c<32;++c) a[c] = ld_sc01_b128(hrecL + (c-16)*16);
    }
    asm volatile("s_waitcnt vmcnt(0)" ::: "memory");
    __builtin_amdgcn_sched_barrier(0);

    // ---- MFMA phase: B-frags streamed from LDS (compiler-pipelined lgkmcnt) ----
    f32x16 acc;
    #pragma unroll
    for (int i=0;i<16;++i) acc[i]=0.f;
    #pragma unroll
    for (int c=0;c<NC;++c){
      bf16x8 wt = *(const bf16x8*)(wcol + ((c*32 + kg16) ^ swz));
      acc = __builtin_amdgcn_mfma_f32_32x32x16_bf16(a[c], wt, acc, 0,0,0);
    }

    // ---- epilogue: 1 transcendental/lane/row; gather gates via shfl ----
    #pragma unroll
    for (int i=0;i<16;++i){
      float v  = acc[i] + bias;
      float vv = q2 ? 2.f*v : v;
      float s  = sigm(vv);
      float act = q2 ? (2.f*s - 1.f) : s;   // tanh for g-gate, sigmoid otherwise
      float a1 = __shfl_xor(act,1,64);      // f (sigm)
      float a2 = __shfl_xor(act,2,64);      // g (tanh)
      float a3 = __shfl_xor(act,3,64);      // o (sigm)
      if ((lane&3)==0){
        float cn = a1*cst[i] + act*a2;
        cst[i] = cn;
        float th = 2.f*sigm(2.f*cn) - 1.f;  // tanh(cn)
        float hv = a3*th;
        int r = (i&3) + 8*(i>>2) + 4*(lane>>5);   // 32x32 C/D row map
        int unit = colL >> 2;
        *(__bf16*)(htile + (m0 + r)*64 + unit*2) = (__bf16)hv;
      }
    }
    __syncthreads();

    // ---- coalesced h-out: 8B/thread, IC-coherent stores ----
    {
      int row = tid>>3, q = tid&7;
      uint64_t v = *(const uint64_t*)(htile + row*64 + q*8);
      st_sc01_b64(hout + (size_t)(b0+row)*Hsz + g*USL + q*4, v);
    }
    asm volatile("s_waitcnt vmcnt(0)" ::: "memory");   // own stores visible at IC
    __syncthreads();                                    // => all block's stores done
    if (tid==0) st_sc01_b32(myflag, (uint32_t)(t+1));
  }
}

__global__ __launch_bounds__(512, 2) void lstm_persist(
    const float* __restrict__ xin,
    const float* __restrict__ Wih0,
    const float* __restrict__ Wih12,
    const float* __restrict__ Whh,
    const float* __restrict__ bih,
    const float* __restrict__ bhh,
    __bf16* __restrict__ hb,
    unsigned int* __restrict__ flags)
{
  // 132 KiB LDS: pins exactly 1 block/CU (guaranteed residency, no co-location)
  __shared__ __align__(16) char smem[WBYTES + HTILE_B];
  const int bid = blockIdx.x;
  const int l   = bid >> 6;
  const int g   = (bid >> 3) & 7;
  const int nb  = bid & 7;
  const int tid = threadIdx.x;
  if (l == 0)
    lstm_body<true >(l,g,nb,tid, xin,Wih0,Wih12,Whh,bih,bhh, hb,flags, smem, smem+WBYTES);
  else
    lstm_body<false>(l,g,nb,tid, xin,Wih0,Wih12,Whh,bih,bhh, hb,flags, smem, smem+WBYTES);
}

__global__ void fc_kernel(const __bf16* __restrict__ hb,
                          const float* __restrict__ fcW,
                          const float* __restrict__ fcb,
                          float* __restrict__ out)
{
  __shared__ float hs[Hsz];
  int b = blockIdx.x;
  const __bf16* hp = hb + ((size_t)(2*PD + ((Tsz-1)&(PD-1))))*Bsz*Hsz + (size_t)b*Hsz;
  for (int i = threadIdx.x; i < Hsz; i += 64) hs[i] = (float)hp[i];
  __syncthreads();
  int o = threadIdx.x;
  if (o < HORZ) {
    float a = fcb[o];
    #pragma unroll 8
    for (int u=0; u<Hsz; ++u) a += hs[u]*fcW[o*Hsz + u];
    out[b*HORZ + o] = a;
  }
}

extern "C" void kernel_launch(void* const* d_in, const int* in_sizes, int n_in,
                              void* d_out, int out_size, void* d_ws, size_t ws_size,
                              hipStream_t stream)
{
  const float* x     = (const float*)d_in[0];
  const float* Wih0  = (const float*)d_in[1];
  const float* Wih12 = (const float*)d_in[2];
  const float* Whh   = (const float*)d_in[3];
  const float* bih   = (const float*)d_in[4];
  const float* bhh   = (const float*)d_in[5];
  const float* fcW   = (const float*)d_in[6];
  const float* fcb   = (const float*)d_in[7];

  __bf16* hb = (__bf16*)d_ws;
  unsigned int* flags = (unsigned int*)((char*)d_ws + HBUF_ELEMS*2);
  size_t clr = HBUF_ELEMS*2 + (size_t)NFLAGS*4;
  hipMemsetAsync(d_ws, 0, clr, stream);   // zero h state + flags (replay-safe)

  hipLaunchKernelGGL(lstm_persist, dim3(3*NG*NBT), dim3(512), 0, stream,
                     x, Wih0, Wih12, Whh, bih, bhh, hb, flags);
  hipLaunchKernelGGL(fc_kernel, dim3(Bsz), dim3(64), 0, stream, hb, fcW, fcb, (float*)d_out);
}

// Round 6
// 3982.778 us; speedup vs baseline: 6.4703x; 1.5174x over previous
//
#include <hip/hip_runtime.h>
#include <hip/hip_bf16.h>
#include <stdint.h>

// Problem constants
#define Bsz 512
#define Tsz 512
#define Fsz 16
#define Hsz 256
#define HORZ 24

// Decomposition: 3 layers x NG gate-slices x NBT batch-tiles = 192 blocks
#define NG 8
#define NBT 8
#define BTILE 64
#define USL 32          // hidden units per slice
#define PD 4            // h parity depth (power of 2)
#define HBUF_ELEMS ((size_t)3*PD*Bsz*Hsz)
#define NFLAGS (3*NG*NBT)
#define AROW_B 1024                 // 1 KiB per A row (512 k * bf16)
#define ABYTES (BTILE*AROW_B)       // 64 KiB staged-A buffer
#define HTILE_B (BTILE*USL*2)       // 4 KiB
#define SMEM_B (84*1024)            // padded -> exactly 1 block/CU

typedef float  f32x4  __attribute__((ext_vector_type(4)));
typedef float  f32x16 __attribute__((ext_vector_type(16)));
typedef __bf16 bf16x8 __attribute__((ext_vector_type(8)));

__device__ __forceinline__ float sigm(float v){ return 1.f/(1.f+__expf(-v)); }

// ---- L1+L2-bypass ops: coherent at the memory-side Infinity Cache.
__device__ __forceinline__ bf16x8 ld_sc01_b128(const void* p){
  bf16x8 r;
  asm volatile("global_load_dwordx4 %0, %1, off sc0 sc1"
    : "=&v"(r) : "v"(p) : "memory");
  return r;
}
__device__ __forceinline__ void st_sc01_b64(void* p, uint64_t v){
  asm volatile("global_store_dwordx2 %0, %1, off sc0 sc1"
    :: "v"(p), "v"(v) : "memory");
}
__device__ __forceinline__ void st_sc01_b32(void* p, uint32_t v){
  asm volatile("global_store_dword %0, %1, off sc0 sc1"
    :: "v"(p), "v"(v) : "memory");
}
__device__ __forceinline__ uint32_t ld_sc01_b32(const void* p){
  uint32_t r;
  asm volatile("global_load_dword %0, %1, off sc0 sc1\n\ts_waitcnt vmcnt(0)"
    : "=&v"(r) : "v"(p) : "memory");
  return r;
}

template<bool L0>
__device__ __forceinline__ void lstm_body(
    int l, int g, int nb, int tid,
    const float* __restrict__ xin,
    const float* __restrict__ Wih0,
    const float* __restrict__ Wih12,
    const float* __restrict__ Whh,
    const float* __restrict__ bih,
    const float* __restrict__ bhh,
    __bf16* __restrict__ hb,
    unsigned int* __restrict__ flags,
    char* alds, char* htile)
{
  const int lane = tid & 63;
  const int wid  = tid >> 6;          // 8 waves: 2M x 4N
  const int wm   = wid >> 2;
  const int wn   = wid & 3;
  const int b0   = nb * BTILE;
  const int m0   = wm * 32;
  const int n0   = wn * 32;

  const int colL = n0 + (lane & 31);            // this lane's gate-col (0..127)
  const int kg8  = (lane >> 5) * 8;             // k offset within chunk (0 or 8)
  const int kg16 = (lane >> 5) * 16;            // byte offset within chunk
  const int R    = (colL&3)*Hsz + g*USL + (colL>>2);   // weight row
  const float bias = bih[l*4*Hsz + R] + bhh[l*4*Hsz + R];
  const int rowA = m0 + (lane & 31);            // batch row within tile

  // ---- one-time: W fragments -> registers/AGPRs (persistent all 512 steps) ----
  constexpr int NC = L0 ? 17 : 32;
  bf16x8 w[NC];
  {
    const float* recB = Whh + ((size_t)l*4*Hsz + R)*Hsz;
    if constexpr (L0) {
      const float* xB = Wih0 + (size_t)R*Fsz;
      #pragma unroll
      for (int c=0;c<17;++c){
        const float* p = (c==0) ? (xB + kg8) : (recB + (c-1)*16 + kg8);
        f32x4 u0 = *(const f32x4*)p;
        f32x4 u1 = *(const f32x4*)(p+4);
        bf16x8 t;
        #pragma unroll
        for (int j=0;j<4;++j){ t[j]=(__bf16)u0[j]; t[j+4]=(__bf16)u1[j]; }
        w[c] = t;
      }
    } else {
      const float* ihB = Wih12 + ((size_t)(l-1)*4*Hsz + R)*Hsz;
      #pragma unroll
      for (int c=0;c<32;++c){
        const float* p = (c<16) ? (ihB + c*16 + kg8) : (recB + (c-16)*16 + kg8);
        f32x4 u0 = *(const f32x4*)p;
        f32x4 u1 = *(const f32x4*)(p+4);
        bf16x8 t;
        #pragma unroll
        for (int j=0;j<4;++j){ t[j]=(__bf16)u0[j]; t[j+4]=(__bf16)u1[j]; }
        w[c] = t;
      }
    }
  }

  // staging role: 8 threads per A-row, 64 B each
  const int srow = tid >> 3;          // 0..63
  const int sks  = tid & 7;           // 0..7
  const int sswz = (srow & 7) << 4;
  char* sdst = alds + srow*AROW_B;
  const size_t sgrow = (size_t)(b0 + srow) * Hsz;

  // fragment-read base for this lane
  const char* arow = alds + rowA*AROW_B;
  const int   aswz = (rowA & 7) << 4;

  float cst[16];
  #pragma unroll
  for (int i=0;i<16;++i) cst[i]=0.f;

  unsigned int* myflag = flags + ((l*NG+g)*NBT + nb);
  const bool q2 = ((colL & 3) == 2);
  __syncthreads();

  for (int t=0; t<Tsz; ++t){
    // ---- point-to-point waits (threads 0..23, one flag each); no cache ops ----
    {
      unsigned int* fp=nullptr; int target=0;
      int grp = tid>>3, gg = tid&7;
      if      (grp==0 && l>0)           { fp = flags + (((l-1)*NG+gg)*NBT+nb); target=t+1; }
      else if (grp==1 && t>0)           { fp = flags + ((l*NG+gg)*NBT+nb);     target=t;   }
      else if (grp==2 && l<2 && t>=PD)  { fp = flags + (((l+1)*NG+gg)*NBT+nb); target=t-(PD-1); }
      if (fp){
        int guard=0;
        while ((int)ld_sc01_b32(fp) < target){
          __builtin_amdgcn_s_sleep(1);
          if (++guard > (1<<22)) break;   // bailout: wrong answer instead of hang
        }
      }
      __syncthreads();
    }

    const size_t hin_off  = ((size_t)((l-1)*PD + (t&(PD-1))))*Bsz*Hsz;
    const size_t hrec_off = ((size_t)(l*PD + ((t+PD-1)&(PD-1))))*Bsz*Hsz;
    __bf16* hout = hb + ((size_t)(l*PD + (t&(PD-1))))*Bsz*Hsz;

    // ---- cooperative A-stage: unique 64KB once per block (no wn duplication) ----
    if constexpr (L0) {
      const __bf16* hr = hb + hrec_off + sgrow + sks*32;
      bf16x8 vr[4];
      #pragma unroll
      for (int j=0;j<4;++j) vr[j] = ld_sc01_b128(hr + j*8);
      bf16x8 vx0, vx1;
      const bool hasx = (sks == 0);
      if (hasx) {   // x chunk: 16 f32 (read-only; cached loads)
        const float* xp = xin + ((size_t)(b0+srow)*Tsz + t)*Fsz;
        f32x4 u0 = *(const f32x4*)xp;
        f32x4 u1 = *(const f32x4*)(xp+4);
        f32x4 u2 = *(const f32x4*)(xp+8);
        f32x4 u3 = *(const f32x4*)(xp+12);
        #pragma unroll
        for (int j=0;j<4;++j){ vx0[j]=(__bf16)u0[j]; vx0[j+4]=(__bf16)u1[j];
                               vx1[j]=(__bf16)u2[j]; vx1[j+4]=(__bf16)u3[j]; }
      }
      asm volatile("s_waitcnt vmcnt(0)" ::: "memory");
      __builtin_amdgcn_sched_barrier(0);
      #pragma unroll
      for (int j=0;j<4;++j)
        *(bf16x8*)(sdst + ((32 + sks*64 + j*16) ^ sswz)) = vr[j];   // hrec bytes 32..543
      if (hasx){
        *(bf16x8*)(sdst + (( 0) ^ sswz)) = vx0;                     // x bytes 0..31
        *(bf16x8*)(sdst + ((16) ^ sswz)) = vx1;
      }
    } else {
      const __bf16* hi = hb + hin_off  + sgrow + sks*32;
      const __bf16* hr = hb + hrec_off + sgrow + sks*32;
      bf16x8 vi[4], vr[4];
      #pragma unroll
      for (int j=0;j<4;++j) vi[j] = ld_sc01_b128(hi + j*8);
      #pragma unroll
      for (int j=0;j<4;++j) vr[j] = ld_sc01_b128(hr + j*8);
      asm volatile("s_waitcnt vmcnt(0)" ::: "memory");
      __builtin_amdgcn_sched_barrier(0);
      #pragma unroll
      for (int j=0;j<4;++j)
        *(bf16x8*)(sdst + ((      sks*64 + j*16) ^ sswz)) = vi[j];  // hin  bytes 0..511
      #pragma unroll
      for (int j=0;j<4;++j)
        *(bf16x8*)(sdst + ((512 + sks*64 + j*16) ^ sswz)) = vr[j];  // hrec bytes 512..1023
    }
    __syncthreads();

    // ---- MFMA phase: A-frags from LDS, W from registers ----
    f32x16 acc;
    #pragma unroll
    for (int i=0;i<16;++i) acc[i]=0.f;
    #pragma unroll
    for (int c=0;c<NC;++c){
      bf16x8 af = *(const bf16x8*)(arow + ((c*32 + kg16) ^ aswz));
      acc = __builtin_amdgcn_mfma_f32_32x32x16_bf16(af, w[c], acc, 0,0,0);
    }

    // ---- epilogue: 1 transcendental/lane/row; gather gates via shfl ----
    #pragma unroll
    for (int i=0;i<16;++i){
      float v  = acc[i] + bias;
      float vv = q2 ? 2.f*v : v;
      float s  = sigm(vv);
      float act = q2 ? (2.f*s - 1.f) : s;   // tanh for g-gate, sigmoid otherwise
      float a1 = __shfl_xor(act,1,64);      // f (sigm)
      float a2 = __shfl_xor(act,2,64);      // g (tanh)
      float a3 = __shfl_xor(act,3,64);      // o (sigm)
      if ((lane&3)==0){
        float cn = a1*cst[i] + act*a2;
        cst[i] = cn;
        float th = 2.f*sigm(2.f*cn) - 1.f;  // tanh(cn)
        float hv = a3*th;
        int r = (i&3) + 8*(i>>2) + 4*(lane>>5);   // 32x32 C/D row map
        int unit = colL >> 2;
        *(__bf16*)(htile + (m0 + r)*64 + unit*2) = (__bf16)hv;
      }
    }
    __syncthreads();

    // ---- coalesced h-out: 8B/thread, IC-coherent stores ----
    {
      int row = tid>>3, q = tid&7;
      uint64_t v = *(const uint64_t*)(htile + row*64 + q*8);
      st_sc01_b64(hout + (size_t)(b0+row)*Hsz + g*USL + q*4, v);
    }
    asm volatile("s_waitcnt vmcnt(0)" ::: "memory");   // own stores visible at IC
    __syncthreads();                                    // => all block's stores done
    if (tid==0) st_sc01_b32(myflag, (uint32_t)(t+1));
  }
}

__global__ __launch_bounds__(512, 2) void lstm_persist(
    const float* __restrict__ xin,
    const float* __restrict__ Wih0,
    const float* __restrict__ Wih12,
    const float* __restrict__ Whh,
    const float* __restrict__ bih,
    const float* __restrict__ bhh,
    __bf16* __restrict__ hb,
    unsigned int* __restrict__ flags)
{
  // 84 KiB LDS: pins exactly 1 block/CU (guaranteed residency, no co-location)
  __shared__ __align__(16) char smem[SMEM_B];
  const int bid = blockIdx.x;
  const int l   = bid >> 6;
  const int g   = (bid >> 3) & 7;
  const int nb  = bid & 7;
  const int tid = threadIdx.x;
  if (l == 0)
    lstm_body<true >(l,g,nb,tid, xin,Wih0,Wih12,Whh,bih,bhh, hb,flags, smem, smem+ABYTES);
  else
    lstm_body<false>(l,g,nb,tid, xin,Wih0,Wih12,Whh,bih,bhh, hb,flags, smem, smem+ABYTES);
}

__global__ void fc_kernel(const __bf16* __restrict__ hb,
                          const float* __restrict__ fcW,
                          const float* __restrict__ fcb,
                          float* __restrict__ out)
{
  __shared__ float hs[Hsz];
  int b = blockIdx.x;
  const __bf16* hp = hb + ((size_t)(2*PD + ((Tsz-1)&(PD-1))))*Bsz*Hsz + (size_t)b*Hsz;
  for (int i = threadIdx.x; i < Hsz; i += 64) hs[i] = (float)hp[i];
  __syncthreads();
  int o = threadIdx.x;
  if (o < HORZ) {
    float a = fcb[o];
    #pragma unroll 8
    for (int u=0; u<Hsz; ++u) a += hs[u]*fcW[o*Hsz + u];
    out[b*HORZ + o] = a;
  }
}

extern "C" void kernel_launch(void* const* d_in, const int* in_sizes, int n_in,
                              void* d_out, int out_size, void* d_ws, size_t ws_size,
                              hipStream_t stream)
{
  const float* x     = (const float*)d_in[0];
  const float* Wih0  = (const float*)d_in[1];
  const float* Wih12 = (const float*)d_in[2];
  const float* Whh   = (const float*)d_in[3];
  const float* bih   = (const float*)d_in[4];
  const float* bhh   = (const float*)d_in[5];
  const float* fcW   = (const float*)d_in[6];
  const float* fcb   = (const float*)d_in[7];

  __bf16* hb = (__bf16*)d_ws;
  unsigned int* flags = (unsigned int*)((char*)d_ws + HBUF_ELEMS*2);
  size_t clr = HBUF_ELEMS*2 + (size_t)NFLAGS*4;
  hipMemsetAsync(d_ws, 0, clr, stream);   // zero h state + flags (replay-safe)

  hipLaunchKernelGGL(lstm_persist, dim3(3*NG*NBT), dim3(512), 0, stream,
                     x, Wih0, Wih12, Whh, bih, bhh, hb, flags);
  hipLaunchKernelGGL(fc_kernel, dim3(Bsz), dim3(64), 0, stream, hb, fcW, fcb, (float*)d_out);
}

// Round 10
// 3918.147 us; speedup vs baseline: 6.5770x; 1.0165x over previous
//
#include <hip/hip_runtime.h>
#include <hip/hip_bf16.h>
#include <stdint.h>

// Problem constants
#define Bsz 512
#define Tsz 512
#define Fsz 16
#define Hsz 256
#define HORZ 24

// 3 layers x 8 gate-slices x 8 batch-tiles = 192 blocks (round-6 geometry)
#define NG 8
#define NBT 8
#define BT 64
#define USL 32          // hidden units per slice (128 gate cols)
#define PD 4            // h slot depth
#define HBUF_ELEMS ((size_t)3*PD*Bsz*Hsz)
#define NFLAGS (3*NG*NBT)
#define AROW_B 512                  // bytes per staged h row (256 bf16)
#define ABUF_B (BT*AROW_B)          // 32 KiB per ain buffer
#define HTILE_B (BT*64)             // 4 KiB
#define SMEM_B (3*ABUF_B + HTILE_B) // 100 KiB -> 1 block/CU

typedef float  f32x4  __attribute__((ext_vector_type(4)));
typedef float  f32x16 __attribute__((ext_vector_type(16)));
typedef __bf16 bf16x8 __attribute__((ext_vector_type(8)));
typedef uint32_t u32x2 __attribute__((ext_vector_type(2)));
typedef uint32_t u32x4 __attribute__((ext_vector_type(4)));

__device__ __forceinline__ float sigm(float v){ return 1.f/(1.f+__expf(-v)); }

// ---- verified sc01 (IC-coherent) helpers; only vmcnt(0) drains anywhere ----
__device__ __forceinline__ bf16x8 ld_sc01_b128(const void* p){   // async
  bf16x8 r;
  asm volatile("global_load_dwordx4 %0, %1, off sc0 sc1" : "=&v"(r) : "v"(p) : "memory");
  return r;
}
__device__ __forceinline__ u32x2 ld_b64_async(const void* p){    // plain cached (x)
  u32x2 r;
  asm volatile("global_load_dwordx2 %0, %1, off" : "=&v"(r) : "v"(p) : "memory");
  return r;
}
__device__ __forceinline__ void st_sc01_b64(void* p, uint64_t v){
  asm volatile("global_store_dwordx2 %0, %1, off sc0 sc1" :: "v"(p), "v"(v) : "memory");
}
__device__ __forceinline__ void st_sc01_b32(void* p, uint32_t v){
  asm volatile("global_store_dword %0, %1, off sc0 sc1" :: "v"(p), "v"(v) : "memory");
}
__device__ __forceinline__ uint32_t ld_sc01_b32(const void* p){  // sync (self-draining)
  uint32_t r;
  asm volatile("global_load_dword %0, %1, off sc0 sc1\n\ts_waitcnt vmcnt(0)"
    : "=&v"(r) : "v"(p) : "memory");
  return r;
}
__device__ __forceinline__ void wait_flag(const unsigned int* fp, int target){
  int guard = 0;
  while ((int)ld_sc01_b32(fp) < target){
    __builtin_amdgcn_s_sleep(1);
    if (++guard > (1<<18)) break;   // fail-fast: wrong result, never a timeout
  }
}

template<bool L0>
__device__ __forceinline__ void lstm_body(
    int l, int g, int nb, int tid,
    const float* __restrict__ xin,
    const float* __restrict__ Wih0,
    const float* __restrict__ Wih12,
    const float* __restrict__ Whh,
    const float* __restrict__ bih,
    const float* __restrict__ bhh,
    __bf16* __restrict__ hb,
    unsigned int* __restrict__ flags,
    char* smem)
{
  char* ain0  = smem;                 // hin buffer parity 0 (L0: x buffer, single)
  char* ain1  = smem + ABUF_B;        // hin buffer parity 1
  char* hrc   = smem + 2*ABUF_B;      // hrec buffer (single)
  char* htile = smem + 3*ABUF_B;      // h-out coalescing tile [64][64B]

  const int lane = tid & 63;
  const int wid  = tid >> 6;          // 8 waves: 2M x 4N
  const int wm   = wid >> 2;
  const int wn   = wid & 3;
  const int b0   = nb * BT;
  const int m0   = wm * 32;
  const int n0   = wn * 32;

  const int colL = n0 + (lane & 31);            // this lane's gate-col (0..127)
  const int hi   = lane >> 5;
  const int kg8  = hi * 8;
  const int kg16 = hi * 16;
  const int R    = (colL&3)*Hsz + g*USL + (colL>>2);   // weight row
  const float bias = bih[l*4*Hsz + R] + bhh[l*4*Hsz + R];
  const int rowA = m0 + (lane & 31);            // batch row within tile
  const int swzA = (rowA & 7) << 4;

  // ---- one-time: W slice -> registers (round-6 verbatim) ----
  constexpr int NC = L0 ? 17 : 32;              // K chunks of 16
  bf16x8 w[NC];
  {
    const float* recB = Whh + ((size_t)l*4*Hsz + R)*Hsz;
    #pragma unroll
    for (int c=0;c<NC;++c){
      const float* p;
      if constexpr (L0) p = (c==0) ? (Wih0 + (size_t)R*Fsz + kg8)
                                   : (recB + (c-1)*16 + kg8);
      else              p = (c<16) ? (Wih12 + ((size_t)(l-1)*4*Hsz + R)*Hsz + c*16 + kg8)
                                   : (recB + (c-16)*16 + kg8);
      f32x4 u0 = *(const f32x4*)p;
      f32x4 u1 = *(const f32x4*)(p+4);
      bf16x8 t;
      #pragma unroll
      for (int j=0;j<4;++j){ t[j]=(__bf16)u0[j]; t[j+4]=(__bf16)u1[j]; }
      w[c] = t;
    }
  }

  // staging roles: 8 threads per 512B row
  const int srow = tid >> 3, sq = tid & 7;
  const int sswz = (srow & 7) << 4;
  const size_t sgrow = (size_t)(b0 + srow) * Hsz;

  float cst[16];
  #pragma unroll
  for (int i=0;i<16;++i) cst[i]=0.f;

  unsigned int* myflag = flags + ((l*NG+g)*NBT + nb);
  const bool q2 = ((colL & 3) == 2);
  auto slotp = [&](int ll, int s){ return hb + ((size_t)ll*PD + (s&3))*Bsz*Hsz; };

  // ---- prologue: zero hrec (h(-1)=0); stage input(0) into ain0 ----
  {
    u32x4 z = {0,0,0,0};
    #pragma unroll
    for (int j=0;j<4;++j) *(u32x4*)(hrc + tid*64 + j*16) = z;
  }
  if constexpr (L0){
    u32x2 xv = ld_b64_async(xin + ((size_t)(b0+srow)*Tsz + 0)*Fsz + sq*2);
    asm volatile("s_waitcnt vmcnt(0)" ::: "memory");
    __builtin_amdgcn_sched_barrier(0);
    char* d = ain0 + srow*32 + sq*4;
    *(__bf16*)(d)   = (__bf16)__uint_as_float(xv[0]);
    *(__bf16*)(d+2) = (__bf16)__uint_as_float(xv[1]);
  } else {
    if (tid < 8) wait_flag(flags + (((l-1)*NG + tid)*NBT + nb), 1);
    __syncthreads();
    const __bf16* src = slotp(l-1,0) + sgrow + sq*32;
    bf16x8 av[4];
    #pragma unroll
    for (int j=0;j<4;++j) av[j] = ld_sc01_b128(src + j*8);
    asm volatile("s_waitcnt vmcnt(0)" ::: "memory");
    __builtin_amdgcn_sched_barrier(0);
    #pragma unroll
    for (int j=0;j<4;++j)
      *(bf16x8*)(ain0 + srow*AROW_B + ((sq*64 + j*16) ^ sswz)) = av[j];
  }
  __syncthreads();

  for (int t=0; t<Tsz; ++t){
    // ---- A: parallel flag waits (8 threads per group) ----
    {
      const unsigned int* fp=nullptr; int target=0;
      int grp = tid>>3, gg = tid&7;
      if      (grp==0 && !L0 && t+1<Tsz) { fp = flags + (((l-1)*NG+gg)*NBT+nb); target=t+2; }
      else if (grp==1 && t>0)            { fp = flags + ((l*NG+gg)*NBT+nb);     target=t;   }
      else if (grp==2 && l<2 && t>=PD)   { fp = flags + (((l+1)*NG+gg)*NBT+nb); target=t-(PD-1); }
      if (fp) wait_flag(fp, target);
      __syncthreads();
    }

    char* aprd = (t&1) ? ain1 : ain0;   // l>=1 hin read buffer
    char* apwr = (t&1) ? ain0 : ain1;   // l>=1 hin prefetch target
    bf16x8 hiv[4];                       // hin(t+1) prefetch regs
    const bool pfon = (!L0) && (t+1 < Tsz);

    // ---- B: hrec stage (one vmcnt(0) RT), then ISSUE hin prefetch ----
    if constexpr (L0){
      u32x2 xv = ld_b64_async(xin + ((size_t)(b0+srow)*Tsz + t)*Fsz + sq*2);
      bf16x8 hrv[4];
      if (t > 0){
        const __bf16* src = slotp(l,t-1) + sgrow + sq*32;
        #pragma unroll
        for (int j=0;j<4;++j) hrv[j] = ld_sc01_b128(src + j*8);
      }
      asm volatile("s_waitcnt vmcnt(0)" ::: "memory");
      __builtin_amdgcn_sched_barrier(0);
      char* d = ain0 + srow*32 + sq*4;
      *(__bf16*)(d)   = (__bf16)__uint_as_float(xv[0]);
      *(__bf16*)(d+2) = (__bf16)__uint_as_float(xv[1]);
      if (t > 0){
        #pragma unroll
        for (int j=0;j<4;++j)
          *(bf16x8*)(hrc + srow*AROW_B + ((sq*64 + j*16) ^ sswz)) = hrv[j];
      }
      __syncthreads();
    } else {
      if (t > 0){
        bf16x8 hrv[4];
        const __bf16* src = slotp(l,t-1) + sgrow + sq*32;
        #pragma unroll
        for (int j=0;j<4;++j) hrv[j] = ld_sc01_b128(src + j*8);
        asm volatile("s_waitcnt vmcnt(0)" ::: "memory");
        __builtin_amdgcn_sched_barrier(0);
        #pragma unroll
        for (int j=0;j<4;++j)
          *(bf16x8*)(hrc + srow*AROW_B + ((sq*64 + j*16) ^ sswz)) = hrv[j];
      }
      if (pfon){   // issue AFTER the drain: flies under MFMA, drained in F
        const __bf16* s2 = slotp(l-1,t+1) + sgrow + sq*32;
        #pragma unroll
        for (int j=0;j<4;++j) hiv[j] = ld_sc01_b128(s2 + j*8);
      }
      __syncthreads();
    }

    // ---- C: MFMA (round-6 verbatim, split A sources) ----
    f32x16 acc;
    #pragma unroll
    for (int i=0;i<16;++i) acc[i]=0.f;
    #pragma unroll
    for (int c=0;c<NC;++c){
      bf16x8 af;
      if constexpr (L0){
        if (c==0) af = *(const bf16x8*)(ain0 + rowA*32 + kg16);
        else      af = *(const bf16x8*)(hrc + rowA*AROW_B + ((((c-1)*32) + kg16) ^ swzA));
      } else {
        if (c<16) af = *(const bf16x8*)(aprd + rowA*AROW_B + (((c*32) + kg16) ^ swzA));
        else      af = *(const bf16x8*)(hrc  + rowA*AROW_B + ((((c-16)*32) + kg16) ^ swzA));
      }
      acc = __builtin_amdgcn_mfma_f32_32x32x16_bf16(af, w[c], acc, 0,0,0);
    }

    // ---- D: epilogue (round-6 verbatim) ----
    #pragma unroll
    for (int i=0;i<16;++i){
      float v  = acc[i] + bias;
      float vv = q2 ? 2.f*v : v;
      float sg = sigm(vv);
      float act = q2 ? (2.f*sg - 1.f) : sg;   // tanh for g-gate, sigmoid otherwise
      float a1 = __shfl_xor(act,1,64);        // f
      float a2 = __shfl_xor(act,2,64);        // g
      float a3 = __shfl_xor(act,3,64);        // o
      if ((lane&3)==0){
        float cn = a1*cst[i] + act*a2;
        cst[i] = cn;
        float th = 2.f*sigm(2.f*cn) - 1.f;    // tanh(cn)
        float hv = a3*th;
        int r = (i&3) + 8*(i>>2) + 4*hi;      // 32x32 C/D row map
        int unit = colL >> 2;
        *(__bf16*)(htile + (m0 + r)*64 + unit*2) = (__bf16)hv;
      }
    }
    __syncthreads();

    // ---- F: h store; single vmcnt(0) drains store + hin prefetch; land hin ----
    {
      uint64_t v = *(const uint64_t*)(htile + srow*64 + sq*8);
      st_sc01_b64(slotp(l,t) + sgrow + g*USL + sq*4, v);
    }
    asm volatile("s_waitcnt vmcnt(0)" ::: "memory");
    __builtin_amdgcn_sched_barrier(0);
    if (pfon){
      #pragma unroll
      for (int j=0;j<4;++j)
        *(bf16x8*)(apwr + srow*AROW_B + ((sq*64 + j*16) ^ sswz)) = hiv[j];
    }
    __syncthreads();                                    // all stores drained
    if (tid==0) st_sc01_b32(myflag, (uint32_t)(t+1));   // flag=v <=> h(v-1) visible
  }
}

__global__ __launch_bounds__(512, 2) void lstm_persist(
    const float* __restrict__ xin,
    const float* __restrict__ Wih0,
    const float* __restrict__ Wih12,
    const float* __restrict__ Whh,
    const float* __restrict__ bih,
    const float* __restrict__ bhh,
    __bf16* __restrict__ hb,
    unsigned int* __restrict__ flags)
{
  __shared__ __align__(16) char smem[SMEM_B];   // 100 KiB -> 1 block/CU
  const int bid = blockIdx.x;
  const int l   = bid >> 6;          // 0..2
  const int g   = (bid >> 3) & 7;    // gate-slice
  const int nb  = bid & 7;           // batch tile
  const int tid = threadIdx.x;
  if (l == 0)
    lstm_body<true >(l,g,nb,tid, xin,Wih0,Wih12,Whh,bih,bhh, hb,flags, smem);
  else
    lstm_body<false>(l,g,nb,tid, xin,Wih0,Wih12,Whh,bih,bhh, hb,flags, smem);
}

__global__ void fc_kernel(const __bf16* __restrict__ hb,
                          const float* __restrict__ fcW,
                          const float* __restrict__ fcb,
                          float* __restrict__ out)
{
  __shared__ float hs[Hsz];
  int b = blockIdx.x;
  const __bf16* hp = hb + ((size_t)(2*PD + ((Tsz-1)&(PD-1))))*Bsz*Hsz + (size_t)b*Hsz;
  for (int i = threadIdx.x; i < Hsz; i += 64) hs[i] = (float)hp[i];
  __syncthreads();
  int o = threadIdx.x;
  if (o < HORZ) {
    float a = fcb[o];
    #pragma unroll 8
    for (int u=0; u<Hsz; ++u) a += hs[u]*fcW[o*Hsz + u];
    out[b*HORZ + o] = a;
  }
}

extern "C" void kernel_launch(void* const* d_in, const int* in_sizes, int n_in,
                              void* d_out, int out_size, void* d_ws, size_t ws_size,
                              hipStream_t stream)
{
  const float* x     = (const float*)d_in[0];
  const float* Wih0  = (const float*)d_in[1];
  const float* Wih12 = (const float*)d_in[2];
  const float* Whh   = (const float*)d_in[3];
  const float* bih   = (const float*)d_in[4];
  const float* bhh   = (const float*)d_in[5];
  const float* fcW   = (const float*)d_in[6];
  const float* fcb   = (const float*)d_in[7];

  __bf16* hb = (__bf16*)d_ws;
  unsigned int* flags = (unsigned int*)((char*)d_ws + HBUF_ELEMS*2);
  size_t clr = HBUF_ELEMS*2 + (size_t)NFLAGS*4;
  hipMemsetAsync(d_ws, 0, clr, stream);   // zero h slots + flags (replay-safe)

  hipLaunchKernelGGL(lstm_persist, dim3(3*NG*NBT), dim3(512), 0, stream,
                     x, Wih0, Wih12, Whh, bih, bhh, hb, flags);
  hipLaunchKernelGGL(fc_kernel, dim3(Bsz), dim3(64), 0, stream, hb, fcW, fcb, (float*)d_out);
}

// Round 11
// 3194.588 us; speedup vs baseline: 8.0666x; 1.2265x over previous
//
#include <hip/hip_runtime.h>
#include <hip/hip_bf16.h>
#include <stdint.h>

// Problem constants
#define Bsz 512
#define Tsz 512
#define Fsz 16
#define Hsz 256
#define HORZ 24

// 3 layers x 8 gate-slices x 8 batch-tiles = 192 blocks (round-6/10 geometry)
#define NG 8
#define NBT 8
#define BT 64
#define USL 32          // hidden units per slice (128 gate cols)
#define PD 8            // h slot depth (power of 2)
#define HBUF_ELEMS ((size_t)3*PD*Bsz*Hsz)
#define NFLAGS (3*NG*NBT)
#define AROW_B 512                  // bytes per staged h row (256 bf16)
#define ABUF_B (BT*AROW_B)          // 32 KiB per ain buffer
#define HTILE_B (BT*64)             // 4 KiB
#define SMEM_B (3*ABUF_B + HTILE_B) // 100 KiB -> 1 block/CU

#define POISON   0x7FC07FC0u                 // bf16 NaN pair: impossible for real h
#define POISON64 0x7FC07FC07FC07FC0ull

typedef float  f32x4  __attribute__((ext_vector_type(4)));
typedef float  f32x16 __attribute__((ext_vector_type(16)));
typedef __bf16 bf16x8 __attribute__((ext_vector_type(8)));
typedef uint32_t u32x2 __attribute__((ext_vector_type(2)));
typedef uint32_t u32x4 __attribute__((ext_vector_type(4)));

__device__ __forceinline__ float sigm(float v){ return 1.f/(1.f+__expf(-v)); }

// ---- verified sc01 (IC-coherent) helpers; only vmcnt(0) drains anywhere ----
__device__ __forceinline__ bf16x8 ld_sc01_b128(const void* p){   // async
  bf16x8 r;
  asm volatile("global_load_dwordx4 %0, %1, off sc0 sc1" : "=&v"(r) : "v"(p) : "memory");
  return r;
}
__device__ __forceinline__ u32x2 ld_b64_async(const void* p){    // plain cached (x)
  u32x2 r;
  asm volatile("global_load_dwordx2 %0, %1, off" : "=&v"(r) : "v"(p) : "memory");
  return r;
}
__device__ __forceinline__ void st_sc01_b64(void* p, uint64_t v){
  asm volatile("global_store_dwordx2 %0, %1, off sc0 sc1" :: "v"(p), "v"(v) : "memory");
}
__device__ __forceinline__ void st_sc01_b32(void* p, uint32_t v){
  asm volatile("global_store_dword %0, %1, off sc0 sc1" :: "v"(p), "v"(v) : "memory");
}
__device__ __forceinline__ uint32_t ld_sc01_b32(const void* p){  // sync (self-draining)
  uint32_t r;
  asm volatile("global_load_dword %0, %1, off sc0 sc1\n\ts_waitcnt vmcnt(0)"
    : "=&v"(r) : "v"(p) : "memory");
  return r;
}
__device__ __forceinline__ void wait_flag(const unsigned int* fp, int target){
  int guard = 0;
  while ((int)ld_sc01_b32(fp) < target){
    __builtin_amdgcn_s_sleep(1);
    if (++guard > (1<<18)) break;   // fail-fast: wrong result, never a timeout
  }
}
__device__ __forceinline__ bool poison_free(const bf16x8* v){
  bool ok = true;
  #pragma unroll
  for (int j=0;j<4;++j){
    u32x4 uv = __builtin_bit_cast(u32x4, v[j]);
    ok = ok && (uv[0] != POISON) && (uv[2] != POISON);   // one check per 8B granule
  }
  return ok;
}
// poll-load 64B until non-poison (steady state: single RT, no retry)
__device__ __forceinline__ void poll_load4(bf16x8* dst, const __bf16* src){
  int guard = 0;
  for(;;){
    #pragma unroll
    for (int j=0;j<4;++j) dst[j] = ld_sc01_b128(src + j*8);
    asm volatile("s_waitcnt vmcnt(0)" ::: "memory");
    __builtin_amdgcn_sched_barrier(0);
    if (poison_free(dst)) break;
    __builtin_amdgcn_s_sleep(4);
    if (++guard > (1<<16)) break;   // fail-fast
  }
}

template<bool L0>
__device__ __forceinline__ void lstm_body(
    int l, int g, int nb, int tid,
    const float* __restrict__ xin,
    const float* __restrict__ Wih0,
    const float* __restrict__ Wih12,
    const float* __restrict__ Whh,
    const float* __restrict__ bih,
    const float* __restrict__ bhh,
    __bf16* __restrict__ hb,
    unsigned int* __restrict__ flags,
    char* smem)
{
  char* ain0  = smem;                 // hin buffer parity 0 (L0: x buffer, single)
  char* ain1  = smem + ABUF_B;        // hin buffer parity 1
  char* hrc   = smem + 2*ABUF_B;      // hrec buffer (single)
  char* htile = smem + 3*ABUF_B;      // h-out coalescing tile [64][64B]

  const int lane = tid & 63;
  const int wid  = tid >> 6;          // 8 waves: 2M x 4N
  const int wm   = wid >> 2;
  const int wn   = wid & 3;
  const int b0   = nb * BT;
  const int m0   = wm * 32;
  const int n0   = wn * 32;

  const int colL = n0 + (lane & 31);            // this lane's gate-col (0..127)
  const int hi   = lane >> 5;
  const int kg8  = hi * 8;
  const int kg16 = hi * 16;
  const int R    = (colL&3)*Hsz + g*USL + (colL>>2);   // weight row
  const float bias = bih[l*4*Hsz + R] + bhh[l*4*Hsz + R];
  const int rowA = m0 + (lane & 31);            // batch row within tile
  const int swzA = (rowA & 7) << 4;

  // ---- one-time: W slice -> registers (round-6 verbatim) ----
  constexpr int NC = L0 ? 17 : 32;              // K chunks of 16
  bf16x8 w[NC];
  {
    const float* recB = Whh + ((size_t)l*4*Hsz + R)*Hsz;
    #pragma unroll
    for (int c=0;c<NC;++c){
      const float* p;
      if constexpr (L0) p = (c==0) ? (Wih0 + (size_t)R*Fsz + kg8)
                                   : (recB + (c-1)*16 + kg8);
      else              p = (c<16) ? (Wih12 + ((size_t)(l-1)*4*Hsz + R)*Hsz + c*16 + kg8)
                                   : (recB + (c-16)*16 + kg8);
      f32x4 u0 = *(const f32x4*)p;
      f32x4 u1 = *(const f32x4*)(p+4);
      bf16x8 t;
      #pragma unroll
      for (int j=0;j<4;++j){ t[j]=(__bf16)u0[j]; t[j+4]=(__bf16)u1[j]; }
      w[c] = t;
    }
  }

  // staging roles: 8 threads per 512B row
  const int srow = tid >> 3, sq = tid & 7;
  const int sswz = (srow & 7) << 4;
  const size_t sgrow = (size_t)(b0 + srow) * Hsz;

  float cst[16];
  #pragma unroll
  for (int i=0;i<16;++i) cst[i]=0.f;

  unsigned int* myflag = flags + ((l*NG+g)*NBT + nb);
  const bool q2 = ((colL & 3) == 2);
  auto slotp = [&](int ll, int s){ return hb + ((size_t)ll*PD + (s&(PD-1)))*Bsz*Hsz; };

  // ---- prologue: zero hrec (h(-1)=0); stage input(0) into ain0 (data-poll) ----
  {
    u32x4 z = {0,0,0,0};
    #pragma unroll
    for (int j=0;j<4;++j) *(u32x4*)(hrc + tid*64 + j*16) = z;
  }
  if constexpr (L0){
    u32x2 xv = ld_b64_async(xin + ((size_t)(b0+srow)*Tsz + 0)*Fsz + sq*2);
    asm volatile("s_waitcnt vmcnt(0)" ::: "memory");
    __builtin_amdgcn_sched_barrier(0);
    char* d = ain0 + srow*32 + sq*4;
    *(__bf16*)(d)   = (__bf16)__uint_as_float(xv[0]);
    *(__bf16*)(d+2) = (__bf16)__uint_as_float(xv[1]);
  } else {
    bf16x8 av[4];
    poll_load4(av, slotp(l-1,0) + sgrow + sq*32);
    #pragma unroll
    for (int j=0;j<4;++j)
      *(bf16x8*)(ain0 + srow*AROW_B + ((sq*64 + j*16) ^ sswz)) = av[j];
  }
  __syncthreads();

  for (int t=0; t<Tsz; ++t){
    // ---- A: lazy WAR guard only (every 4 steps; off critical path) ----
    if (l < 2 && (t & 3) == 0){
      if (tid < 8 && t >= 4)
        wait_flag(flags + (((l+1)*NG + tid)*NBT + nb), t-3);
      __syncthreads();
    }

    char* aprd = (t&1) ? ain1 : ain0;   // l>=1 hin read buffer
    char* apwr = (t&1) ? ain0 : ain1;   // l>=1 hin prefetch target
    bf16x8 hiv[4];                       // hin(t+1) prefetch regs
    const __bf16* pfsrc = nullptr;
    const bool pfon = (!L0) && (t+1 < Tsz);

    // ---- B: hrec DATA-POLL (1 RT steady state); then issue hin prefetch ----
    if constexpr (L0){
      u32x2 xv = ld_b64_async(xin + ((size_t)(b0+srow)*Tsz + t)*Fsz + sq*2);
      bf16x8 hrv[4];
      if (t > 0) poll_load4(hrv, slotp(l,t-1) + sgrow + sq*32);
      else { asm volatile("s_waitcnt vmcnt(0)" ::: "memory");
             __builtin_amdgcn_sched_barrier(0); }
      char* d = ain0 + srow*32 + sq*4;
      *(__bf16*)(d)   = (__bf16)__uint_as_float(xv[0]);
      *(__bf16*)(d+2) = (__bf16)__uint_as_float(xv[1]);
      if (t > 0){
        #pragma unroll
        for (int j=0;j<4;++j)
          *(bf16x8*)(hrc + srow*AROW_B + ((sq*64 + j*16) ^ sswz)) = hrv[j];
      }
      __syncthreads();
    } else {
      if (t > 0){
        bf16x8 hrv[4];
        poll_load4(hrv, slotp(l,t-1) + sgrow + sq*32);
        #pragma unroll
        for (int j=0;j<4;++j)
          *(bf16x8*)(hrc + srow*AROW_B + ((sq*64 + j*16) ^ sswz)) = hrv[j];
      }
      if (pfon){   // issue async; flies under MFMA, drained+checked in F
        pfsrc = slotp(l-1,t+1) + sgrow + sq*32;
        #pragma unroll
        for (int j=0;j<4;++j) hiv[j] = ld_sc01_b128(pfsrc + j*8);
      }
      __syncthreads();
    }

    // ---- C: MFMA (round-6 verbatim, split A sources) ----
    f32x16 acc;
    #pragma unroll
    for (int i=0;i<16;++i) acc[i]=0.f;
    #pragma unroll
    for (int c=0;c<NC;++c){
      bf16x8 af;
      if constexpr (L0){
        if (c==0) af = *(const bf16x8*)(ain0 + rowA*32 + kg16);
        else      af = *(const bf16x8*)(hrc + rowA*AROW_B + ((((c-1)*32) + kg16) ^ swzA));
      } else {
        if (c<16) af = *(const bf16x8*)(aprd + rowA*AROW_B + (((c*32) + kg16) ^ swzA));
        else      af = *(const bf16x8*)(hrc  + rowA*AROW_B + ((((c-16)*32) + kg16) ^ swzA));
      }
      acc = __builtin_amdgcn_mfma_f32_32x32x16_bf16(af, w[c], acc, 0,0,0);
    }

    // ---- D: epilogue (round-6 verbatim) ----
    #pragma unroll
    for (int i=0;i<16;++i){
      float v  = acc[i] + bias;
      float vv = q2 ? 2.f*v : v;
      float sg = sigm(vv);
      float act = q2 ? (2.f*sg - 1.f) : sg;   // tanh for g-gate, sigmoid otherwise
      float a1 = __shfl_xor(act,1,64);        // f
      float a2 = __shfl_xor(act,2,64);        // g
      float a3 = __shfl_xor(act,3,64);        // o
      if ((lane&3)==0){
        float cn = a1*cst[i] + act*a2;
        cst[i] = cn;
        float th = 2.f*sigm(2.f*cn) - 1.f;    // tanh(cn)
        float hv = a3*th;
        int r = (i&3) + 8*(i>>2) + 4*hi;      // 32x32 C/D row map
        int unit = colL >> 2;
        *(__bf16*)(htile + (m0 + r)*64 + unit*2) = (__bf16)hv;
      }
    }
    __syncthreads();

    // ---- F: h store + forward poison; drain; check+land hin; publish ----
    {
      uint64_t v = *(const uint64_t*)(htile + srow*64 + sq*8);
      st_sc01_b64(slotp(l,t)   + sgrow + g*USL + sq*4, v);
      st_sc01_b64(slotp(l,t+2) + sgrow + g*USL + sq*4, POISON64);  // pre-poison slot t+2
    }
    asm volatile("s_waitcnt vmcnt(0)" ::: "memory");   // drains stores + prefetch loads
    __builtin_amdgcn_sched_barrier(0);
    if (pfon){
      if (!poison_free(hiv)) poll_load4(hiv, pfsrc);   // rare: l-1 not there yet
      #pragma unroll
      for (int j=0;j<4;++j)
        *(bf16x8*)(apwr + srow*AROW_B + ((sq*64 + j*16) ^ sswz)) = hiv[j];
    }
    __syncthreads();
    if (tid==0) st_sc01_b32(myflag, (uint32_t)(t+1));  // progress marker (WAR only)
  }
}

__global__ __launch_bounds__(512, 2) void lstm_persist(
    const float* __restrict__ xin,
    const float* __restrict__ Wih0,
    const float* __restrict__ Wih12,
    const float* __restrict__ Whh,
    const float* __restrict__ bih,
    const float* __restrict__ bhh,
    __bf16* __restrict__ hb,
    unsigned int* __restrict__ flags)
{
  __shared__ __align__(16) char smem[SMEM_B];   // 100 KiB -> 1 block/CU
  const int bid = blockIdx.x;
  const int l   = bid >> 6;          // 0..2
  const int g   = (bid >> 3) & 7;    // gate-slice
  const int nb  = bid & 7;           // batch tile
  const int tid = threadIdx.x;
  if (l == 0)
    lstm_body<true >(l,g,nb,tid, xin,Wih0,Wih12,Whh,bih,bhh, hb,flags, smem);
  else
    lstm_body<false>(l,g,nb,tid, xin,Wih0,Wih12,Whh,bih,bhh, hb,flags, smem);
}

// Pre-fill all h slots with NaN poison + zero flags (replay-safe init)
__global__ void init_ws(uint32_t* __restrict__ hb32, uint32_t* __restrict__ flags)
{
  size_t i = (size_t)blockIdx.x*blockDim.x + threadIdx.x;
  size_t n = (HBUF_ELEMS*2)/16;   // #u32x4 chunks
  if (i < n){
    u32x4 v = {POISON, POISON, POISON, POISON};
    *(u32x4*)(hb32 + i*4) = v;
  }
  if (i < NFLAGS) flags[i] = 0;
}

__global__ void fc_kernel(const __bf16* __restrict__ hb,
                          const float* __restrict__ fcW,
                          const float* __restrict__ fcb,
                          float* __restrict__ out)
{
  __shared__ float hs[Hsz];
  int b = blockIdx.x;
  const __bf16* hp = hb + ((size_t)(2*PD + ((Tsz-1)&(PD-1))))*Bsz*Hsz + (size_t)b*Hsz;
  for (int i = threadIdx.x; i < Hsz; i += 64) hs[i] = (float)hp[i];
  __syncthreads();
  int o = threadIdx.x;
  if (o < HORZ) {
    float a = fcb[o];
    #pragma unroll 8
    for (int u=0; u<Hsz; ++u) a += hs[u]*fcW[o*Hsz + u];
    out[b*HORZ + o] = a;
  }
}

extern "C" void kernel_launch(void* const* d_in, const int* in_sizes, int n_in,
                              void* d_out, int out_size, void* d_ws, size_t ws_size,
                              hipStream_t stream)
{
  const float* x     = (const float*)d_in[0];
  const float* Wih0  = (const float*)d_in[1];
  const float* Wih12 = (const float*)d_in[2];
  const float* Whh   = (const float*)d_in[3];
  const float* bih   = (const float*)d_in[4];
  const float* bhh   = (const float*)d_in[5];
  const float* fcW   = (const float*)d_in[6];
  const float* fcb   = (const float*)d_in[7];

  __bf16* hb = (__bf16*)d_ws;
  unsigned int* flags = (unsigned int*)((char*)d_ws + HBUF_ELEMS*2);

  // poison h slots + zero flags (kernel, since memset can't write 0x7FC07FC0)
  size_t nchunk = (HBUF_ELEMS*2)/16;
  int ib = (int)((nchunk + 255) / 256);
  hipLaunchKernelGGL(init_ws, dim3(ib), dim3(256), 0, stream, (uint32_t*)hb, flags);

  hipLaunchKernelGGL(lstm_persist, dim3(3*NG*NBT), dim3(512), 0, stream,
                     x, Wih0, Wih12, Whh, bih, bhh, hb, flags);
  hipLaunchKernelGGL(fc_kernel, dim3(Bsz), dim3(64), 0, stream, hb, fcW, fcb, (float*)d_out);
}